// Round 1
// baseline (1361.470 us; speedup 1.0000x reference)
//
#include <hip/hip_runtime.h>

#define BB 32
#define LL 128
#define CC 1024
#define EE 256
#define NH 4
#define HD 64

__device__ __forceinline__ void fma4(float4& a, float s, const float4 v) {
    a.x = fmaf(s, v.x, a.x); a.y = fmaf(s, v.y, a.y);
    a.z = fmaf(s, v.z, a.z); a.w = fmaf(s, v.w, a.w);
}

// ---------------- K1: SE adaptive-avg-pool  y0[b,i] = mean of 128 contiguous floats
__global__ __launch_bounds__(256) void k_pool(const float* __restrict__ x,
                                              float* __restrict__ y0) {
    int t = threadIdx.x;
    int lane = t & 63;
    int v = blockIdx.x * 4 + (t >> 6);            // 0..32767  (b*1024 + i)
    const float2* p = (const float2*)(x + (size_t)v * 128);
    float2 d = p[lane];
    float s = d.x + d.y;
    #pragma unroll
    for (int m = 1; m < 64; m <<= 1) s += __shfl_xor(s, m, 64);
    if (lane == 0) y0[v] = s * (1.0f / 128.0f);
}

// ---------------- K2/K3: SE fc layers.  out[b,i] = act( sum_c in[b,c]*w[i,c] )
template <int ACT>   // 0 = relu, 1 = sigmoid
__global__ __launch_bounds__(256) void k_se_fc(const float* __restrict__ in,
                                               const float* __restrict__ w,
                                               float* __restrict__ outp) {
    __shared__ float yin[1024];
    int b = blockIdx.x >> 2;
    int it = blockIdx.x & 3;
    int t = threadIdx.x;
    for (int i = t; i < 1024; i += 256) yin[i] = in[b * 1024 + i];
    __syncthreads();
    int i = it * 256 + t;
    const float4* wr = (const float4*)(w + (size_t)i * 1024);
    float acc = 0.f;
    #pragma unroll 4
    for (int c4 = 0; c4 < 256; ++c4) {
        float4 wv = wr[c4];
        const float* yy = &yin[c4 * 4];
        acc += wv.x * yy[0] + wv.y * yy[1] + wv.z * yy[2] + wv.w * yy[3];
    }
    float r = (ACT == 0) ? fmaxf(acc, 0.f) : (1.f / (1.f + expf(-acc)));
    outp[b * 1024 + i] = r;
}

// ---------------- K4: fused SE-scale + 1x1 conv over L.
// xg[b,c,e] = sum_l ws[e,l] * x[b,l,c] * y[b, 8l + (c>>7)]
__global__ __launch_bounds__(256) void k_conv(const float* __restrict__ x,
                                              const float* __restrict__ wsi,
                                              const float* __restrict__ y,
                                              float* __restrict__ xg) {
    __shared__ __align__(16) float wsT[32 * 260];   // [l' in chunk][e], pad 260
    __shared__ __align__(16) float xl[32 * 32];     // [l'][c]
    __shared__ float sl[128];
    int b = blockIdx.x >> 5, ct = blockIdx.x & 31;
    int c0 = ct * 32;
    int t = threadIdx.x;
    if (t < 128) sl[t] = y[b * 1024 + 8 * t + (c0 >> 7)];
    int e4 = (t & 63) * 4, cq = t >> 6;
    float acc[4][8];
    #pragma unroll
    for (int i = 0; i < 4; ++i)
        #pragma unroll
        for (int j = 0; j < 8; ++j) acc[i][j] = 0.f;

    for (int lc = 0; lc < 4; ++lc) {
        __syncthreads();
        for (int idx = t; idx < 8192; idx += 256) {      // ws chunk [32 l'][256 e] transposed
            int e = idx >> 5, lp = idx & 31;
            wsT[lp * 260 + e] = wsi[e * 128 + lc * 32 + lp];
        }
        {
            int c = t & 31, l0 = t >> 5;
            for (int lp = l0; lp < 32; lp += 8)
                xl[lp * 32 + c] = x[(size_t)b * 131072 + (size_t)(lc * 32 + lp) * 1024 + c0 + c];
        }
        __syncthreads();
        for (int lp = 0; lp < 32; ++lp) {
            float s = sl[lc * 32 + lp];
            float4 wv = *(const float4*)&wsT[lp * 260 + e4];
            float4 x0 = *(const float4*)&xl[lp * 32 + cq * 8];
            float4 x1 = *(const float4*)&xl[lp * 32 + cq * 8 + 4];
            float w0 = wv.x * s, w1 = wv.y * s, w2 = wv.z * s, w3 = wv.w * s;
            float xc[8] = {x0.x, x0.y, x0.z, x0.w, x1.x, x1.y, x1.z, x1.w};
            #pragma unroll
            for (int ci = 0; ci < 8; ++ci) {
                acc[0][ci] = fmaf(w0, xc[ci], acc[0][ci]);
                acc[1][ci] = fmaf(w1, xc[ci], acc[1][ci]);
                acc[2][ci] = fmaf(w2, xc[ci], acc[2][ci]);
                acc[3][ci] = fmaf(w3, xc[ci], acc[3][ci]);
            }
        }
    }
    size_t base = (size_t)b * CC * EE;
    #pragma unroll
    for (int ci = 0; ci < 8; ++ci) {
        int c = c0 + cq * 8 + ci;
        float4 o = make_float4(acc[0][ci], acc[1][ci], acc[2][ci], acc[3][ci]);
        *(float4*)&xg[base + (size_t)c * EE + e4] = o;
    }
}

// ---------------- K5: packed q,k projection (v skipped).
// qk[bc, col] = bias[col] + sum_e' xg[bc,e'] * W[col,e'],  col in [0,512)
__global__ __launch_bounds__(256) void k_qkv(const float* __restrict__ xg,
                                             const float* __restrict__ W,
                                             const float* __restrict__ bias,
                                             float* __restrict__ qk) {
    __shared__ __align__(16) float Al[64 * 64];   // [kk][m] xor-swizzled
    __shared__ __align__(16) float Bl[64 * 64];   // [kk][n] xor-swizzled
    int rt = blockIdx.x >> 3, ct = blockIdx.x & 7;
    int row0 = rt * 64, col0 = ct * 64;
    int t = threadIdx.x, tx = t & 15, ty = t >> 4;
    float4 acc[4];
    acc[0] = acc[1] = acc[2] = acc[3] = make_float4(0, 0, 0, 0);
    int k4 = (t & 15) * 4, rr0 = t >> 4;
    for (int kt = 0; kt < 4; ++kt) {
        for (int rr = rr0; rr < 64; rr += 16) {
            float4 v = *(const float4*)&xg[(size_t)(row0 + rr) * EE + kt * 64 + k4];
            float vv[4] = {v.x, v.y, v.z, v.w};
            float4 w = *(const float4*)&W[(size_t)(col0 + rr) * EE + kt * 64 + k4];
            float ww[4] = {w.x, w.y, w.z, w.w};
            #pragma unroll
            for (int i = 0; i < 4; ++i) {
                int kk = k4 + i;
                int idx = kk * 64 + (((((rr >> 2) ^ (kk >> 2)) & 15) << 2) | (rr & 3));
                Al[idx] = vv[i];
                Bl[idx] = ww[i];
            }
        }
        __syncthreads();
        #pragma unroll 8
        for (int kk = 0; kk < 64; ++kk) {
            int s4 = (kk >> 2) & 15;
            float4 a = *(const float4*)&Al[kk * 64 + (((ty ^ s4) & 15) << 2)];
            float4 bv = *(const float4*)&Bl[kk * 64 + (((tx ^ s4) & 15) << 2)];
            fma4(acc[0], a.x, bv); fma4(acc[1], a.y, bv);
            fma4(acc[2], a.z, bv); fma4(acc[3], a.w, bv);
        }
        __syncthreads();
    }
    float4 bb = *(const float4*)&bias[col0 + tx * 4];
    #pragma unroll
    for (int i = 0; i < 4; ++i) {
        float4 v = acc[i];
        v.x += bb.x; v.y += bb.y; v.z += bb.z; v.w += bb.w;
        *(float4*)&qk[(size_t)(row0 + ty * 4 + i) * 512 + col0 + tx * 4] = v;
    }
}

// ---------------- K6: b_adj = mean_h softmax(q_h k_h^T / 8).  Writes into d_out.
// Block = (b, 32 q-rows). 4 waves = 4 heads. Two passes (sum, then normalize+write).
__global__ __launch_bounds__(256) void k_attn(const float* __restrict__ qk,
                                              float* __restrict__ badj) {
    __shared__ __align__(16) float qT[256 * 32];   // [dd][r] xor-swizzled (3-bit)
    __shared__ __align__(16) float kT[256 * 32];   // [dd][kc] xor-swizzled
    __shared__ float sums[4 * 32];
    __shared__ float accL[32 * 33];
    const float SCL = 0.125f;
    int b = blockIdx.x >> 5, qt = blockIdx.x & 31;
    int q0 = qt * 32;
    int t = threadIdx.x;
    int g = t >> 6;                 // wave id = head
    int lane = t & 63;
    int tx = lane & 7, ty = lane >> 3;
    size_t qkbase = (size_t)b * 1024 * 512;

    // stage qT once: q cols 0..255 of rows q0..q0+31, transposed+swizzled
    {
        int dd4 = (t & 63) * 4, r0 = t >> 6;
        for (int r = r0; r < 32; r += 4) {
            float4 v = *(const float4*)&qk[qkbase + (size_t)(q0 + r) * 512 + dd4];
            float vv[4] = {v.x, v.y, v.z, v.w};
            #pragma unroll
            for (int i = 0; i < 4; ++i) {
                int dd = dd4 + i, sw = (dd >> 2) & 7;
                qT[dd * 32 + ((((r >> 2) ^ sw) & 7) << 2) + (r & 3)] = vv[i];
            }
        }
    }

    float rsum[4] = {0.f, 0.f, 0.f, 0.f};
    // ---- pass 1: row sums of exp(scores)
    for (int kt2 = 0; kt2 < 32; ++kt2) {
        __syncthreads();
        {
            int dd4 = (t & 63) * 4, k0 = t >> 6;
            for (int kc = k0; kc < 32; kc += 4) {
                float4 v = *(const float4*)&qk[qkbase + (size_t)(kt2 * 32 + kc) * 512 + 256 + dd4];
                float vv[4] = {v.x, v.y, v.z, v.w};
                #pragma unroll
                for (int i = 0; i < 4; ++i) {
                    int dd = dd4 + i, sw = (dd >> 2) & 7;
                    kT[dd * 32 + ((((kc >> 2) ^ sw) & 7) << 2) + (kc & 3)] = vv[i];
                }
            }
        }
        __syncthreads();
        float4 accS[4];
        accS[0] = accS[1] = accS[2] = accS[3] = make_float4(0, 0, 0, 0);
        #pragma unroll 8
        for (int kk = 0; kk < 64; ++kk) {
            int dd = g * 64 + kk;
            int sw = (dd >> 2) & 7;
            float4 a = *(const float4*)&qT[dd * 32 + (((ty ^ sw) & 7) << 2)];
            float4 bv = *(const float4*)&kT[dd * 32 + (((tx ^ sw) & 7) << 2)];
            fma4(accS[0], a.x, bv); fma4(accS[1], a.y, bv);
            fma4(accS[2], a.z, bv); fma4(accS[3], a.w, bv);
        }
        #pragma unroll
        for (int i = 0; i < 4; ++i)
            rsum[i] += expf(accS[i].x * SCL) + expf(accS[i].y * SCL) +
                       expf(accS[i].z * SCL) + expf(accS[i].w * SCL);
    }
    // reduce rsum over tx lanes (bits 0..2)
    #pragma unroll
    for (int i = 0; i < 4; ++i) {
        float s = rsum[i];
        s += __shfl_xor(s, 1, 64);
        s += __shfl_xor(s, 2, 64);
        s += __shfl_xor(s, 4, 64);
        if (tx == 0) sums[g * 32 + ty * 4 + i] = s;
    }
    __syncthreads();
    float inv[4];
    #pragma unroll
    for (int i = 0; i < 4; ++i) inv[i] = 0.25f / sums[g * 32 + ty * 4 + i];

    // ---- pass 2: recompute, normalize, sum heads, write
    for (int kt2 = 0; kt2 < 32; ++kt2) {
        __syncthreads();
        {
            int dd4 = (t & 63) * 4, k0 = t >> 6;
            for (int kc = k0; kc < 32; kc += 4) {
                float4 v = *(const float4*)&qk[qkbase + (size_t)(kt2 * 32 + kc) * 512 + 256 + dd4];
                float vv[4] = {v.x, v.y, v.z, v.w};
                #pragma unroll
                for (int i = 0; i < 4; ++i) {
                    int dd = dd4 + i, sw = (dd >> 2) & 7;
                    kT[dd * 32 + ((((kc >> 2) ^ sw) & 7) << 2) + (kc & 3)] = vv[i];
                }
            }
        }
        for (int f = t; f < 32 * 33; f += 256) accL[f] = 0.f;
        __syncthreads();
        float4 accS[4];
        accS[0] = accS[1] = accS[2] = accS[3] = make_float4(0, 0, 0, 0);
        #pragma unroll 8
        for (int kk = 0; kk < 64; ++kk) {
            int dd = g * 64 + kk;
            int sw = (dd >> 2) & 7;
            float4 a = *(const float4*)&qT[dd * 32 + (((ty ^ sw) & 7) << 2)];
            float4 bv = *(const float4*)&kT[dd * 32 + (((tx ^ sw) & 7) << 2)];
            fma4(accS[0], a.x, bv); fma4(accS[1], a.y, bv);
            fma4(accS[2], a.z, bv); fma4(accS[3], a.w, bv);
        }
        float p[4][4];
        #pragma unroll
        for (int i = 0; i < 4; ++i) {
            p[i][0] = expf(accS[i].x * SCL) * inv[i];
            p[i][1] = expf(accS[i].y * SCL) * inv[i];
            p[i][2] = expf(accS[i].z * SCL) * inv[i];
            p[i][3] = expf(accS[i].w * SCL) * inv[i];
        }
        for (int hturn = 0; hturn < 4; ++hturn) {
            if (g == hturn) {
                #pragma unroll
                for (int i = 0; i < 4; ++i)
                    #pragma unroll
                    for (int j = 0; j < 4; ++j)
                        accL[(ty * 4 + i) * 33 + tx * 4 + j] += p[i][j];
            }
            __syncthreads();
        }
        {
            int kc = t & 31, r0 = t >> 5;
            for (int r = r0; r < 32; r += 8)
                badj[(size_t)b * 1048576 + (size_t)(q0 + r) * 1024 + kt2 * 32 + kc] =
                    accL[r * 33 + kc];
        }
    }
}

// ---------------- K6b: bxg = b_adj @ xg   (per b: [1024x1024]@[1024x256])
__global__ __launch_bounds__(256) void k_badjxg(const float* __restrict__ badj,
                                                const float* __restrict__ xg,
                                                float* __restrict__ bxg) {
    __shared__ __align__(16) float Al[64 * 64];   // [kk][m] swizzled
    __shared__ __align__(16) float Bl[64 * 68];   // [kk][n] straight, pad 68
    int bb = blockIdx.x >> 6;
    int mt = (blockIdx.x >> 2) & 15, nt = blockIdx.x & 3;
    int m0 = mt * 64, n0 = nt * 64;
    int t = threadIdx.x, tx = t & 15, ty = t >> 4;
    float4 acc[4];
    acc[0] = acc[1] = acc[2] = acc[3] = make_float4(0, 0, 0, 0);
    int k4 = (t & 15) * 4, rr0 = t >> 4;
    for (int kt = 0; kt < 16; ++kt) {
        for (int rr = rr0; rr < 64; rr += 16) {
            float4 v = *(const float4*)&badj[(size_t)bb * 1048576 + (size_t)(m0 + rr) * 1024 + kt * 64 + k4];
            float vv[4] = {v.x, v.y, v.z, v.w};
            #pragma unroll
            for (int i = 0; i < 4; ++i) {
                int kk = k4 + i;
                Al[kk * 64 + (((((rr >> 2) ^ (kk >> 2)) & 15) << 2) | (rr & 3))] = vv[i];
            }
        }
        {
            int n4 = (t & 15) * 4, kk0 = t >> 4;
            for (int kk = kk0; kk < 64; kk += 16)
                *(float4*)&Bl[kk * 68 + n4] =
                    *(const float4*)&xg[(size_t)(bb * 1024 + kt * 64 + kk) * EE + n0 + n4];
        }
        __syncthreads();
        #pragma unroll 8
        for (int kk = 0; kk < 64; ++kk) {
            int s4 = (kk >> 2) & 15;
            float4 a = *(const float4*)&Al[kk * 64 + (((ty ^ s4) & 15) << 2)];
            float4 bv = *(const float4*)&Bl[kk * 68 + tx * 4];
            fma4(acc[0], a.x, bv); fma4(acc[1], a.y, bv);
            fma4(acc[2], a.z, bv); fma4(acc[3], a.w, bv);
        }
        __syncthreads();
    }
    #pragma unroll
    for (int i = 0; i < 4; ++i)
        *(float4*)&bxg[(size_t)(bb * 1024 + m0 + ty * 4 + i) * EE + n0 + tx * 4] = acc[i];
}

// ---------------- K7: cheb = xg@theta0 + bxg@theta1   ([B,1024,256])
__global__ __launch_bounds__(256) void k_cheb(const float* __restrict__ xg,
                                              const float* __restrict__ bxg,
                                              const float* __restrict__ theta,
                                              float* __restrict__ cheb) {
    __shared__ __align__(16) float Al[64 * 64];
    __shared__ __align__(16) float Bl[64 * 68];
    int bb = blockIdx.x >> 6;
    int mt = (blockIdx.x >> 2) & 15, nt = blockIdx.x & 3;
    int m0 = mt * 64, n0 = nt * 64;
    int t = threadIdx.x, tx = t & 15, ty = t >> 4;
    float4 acc[4];
    acc[0] = acc[1] = acc[2] = acc[3] = make_float4(0, 0, 0, 0);
    int k4 = (t & 15) * 4, rr0 = t >> 4;
    for (int ph = 0; ph < 2; ++ph) {
        const float* A = ph ? bxg : xg;
        const float* Bm = theta + (size_t)ph * 65536;
        for (int kt = 0; kt < 4; ++kt) {
            for (int rr = rr0; rr < 64; rr += 16) {
                float4 v = *(const float4*)&A[(size_t)(bb * 1024 + m0 + rr) * EE + kt * 64 + k4];
                float vv[4] = {v.x, v.y, v.z, v.w};
                #pragma unroll
                for (int i = 0; i < 4; ++i) {
                    int kk = k4 + i;
                    Al[kk * 64 + (((((rr >> 2) ^ (kk >> 2)) & 15) << 2) | (rr & 3))] = vv[i];
                }
            }
            {
                int n4 = (t & 15) * 4, kk0 = t >> 4;
                for (int kk = kk0; kk < 64; kk += 16)
                    *(float4*)&Bl[kk * 68 + n4] =
                        *(const float4*)&Bm[(size_t)(kt * 64 + kk) * EE + n0 + n4];
            }
            __syncthreads();
            #pragma unroll 8
            for (int kk = 0; kk < 64; ++kk) {
                int s4 = (kk >> 2) & 15;
                float4 a = *(const float4*)&Al[kk * 64 + (((ty ^ s4) & 15) << 2)];
                float4 bv = *(const float4*)&Bl[kk * 68 + tx * 4];
                fma4(acc[0], a.x, bv); fma4(acc[1], a.y, bv);
                fma4(acc[2], a.z, bv); fma4(acc[3], a.w, bv);
            }
            __syncthreads();
        }
    }
    #pragma unroll
    for (int i = 0; i < 4; ++i)
        *(float4*)&cheb[(size_t)(bb * 1024 + m0 + ty * 4 + i) * EE + n0 + tx * 4] = acc[i];
}

// ---------------- K8: out[b,e,c] = relu( xg[b,c,e] + relu(cheb[b, 4e+(c>>8), c&255]) )
__global__ __launch_bounds__(256) void k_final(const float* __restrict__ xg,
                                               const float* __restrict__ cheb,
                                               float* __restrict__ outp) {
    __shared__ float xl[256 * 33];
    int b = blockIdx.x >> 5;
    int et = (blockIdx.x >> 2) & 7, cb = blockIdx.x & 3;
    int e0 = et * 32, c0 = cb * 256;
    int t = threadIdx.x;
    {
        int e = t & 31, cl0 = t >> 5;
        for (int c = cl0; c < 256; c += 8)
            xl[c * 33 + e] = xg[((size_t)b * 1024 + c0 + c) * EE + e0 + e];
    }
    __syncthreads();
    int q4 = c0 >> 8;
    for (int el = 0; el < 32; ++el) {
        int e = e0 + el;
        float ch = cheb[((size_t)b * 1024 + e * 4 + q4) * EE + t];
        float v = fmaxf(ch, 0.f);
        float xin = xl[t * 33 + el];
        outp[((size_t)b * 256 + e) * 1024 + c0 + t] = fmaxf(xin + v, 0.f);
    }
}

extern "C" void kernel_launch(void* const* d_in, const int* in_sizes, int n_in,
                              void* d_out, int out_size, void* d_ws, size_t ws_size,
                              hipStream_t stream) {
    const float* x     = (const float*)d_in[0];
    const float* w1    = (const float*)d_in[1];
    const float* w2    = (const float*)d_in[2];
    const float* wsi   = (const float*)d_in[3];
    const float* wqkv  = (const float*)d_in[4];
    const float* bqkv  = (const float*)d_in[5];
    const float* theta = (const float*)d_in[6];

    float* out  = (float*)d_out;
    float* badj = out + (size_t)BB * EE * CC;      // second output, 32*1024*1024

    // workspace layout (floats), total exactly 128 MiB:
    //   xg  [B,C,E]   @ 0          (8,388,608)
    //   qk  [B*C,512] @ 8,388,608  (16,777,216)  -- cheb aliases this after attn
    //   bxg [B,C,E]   @ 25,165,824 (8,388,608)
    //   SE buffers alias the (not yet written) qk region.
    float* wsf  = (float*)d_ws;
    float* xg   = wsf;
    float* qk   = wsf + 8388608;
    float* cheb = qk;
    float* bxg  = wsf + 25165824;
    float* y0   = qk;            // B*C, dead before k_qkv writes qk
    float* hh   = qk + 32768;
    float* yy   = qk + 65536;

    k_pool   <<<8192, 256, 0, stream>>>(x, y0);
    k_se_fc<0><<<128, 256, 0, stream>>>(y0, w1, hh);
    k_se_fc<1><<<128, 256, 0, stream>>>(hh, w2, yy);
    k_conv   <<<1024, 256, 0, stream>>>(x, wsi, yy, xg);
    k_qkv    <<<4096, 256, 0, stream>>>(xg, wqkv, bqkv, qk);
    k_attn   <<<1024, 256, 0, stream>>>(qk, badj);
    k_badjxg <<<2048, 256, 0, stream>>>(badj, xg, bxg);
    k_cheb   <<<2048, 256, 0, stream>>>(xg, bxg, theta, cheb);
    k_final  <<<1024, 256, 0, stream>>>(xg, cheb, out);
}

// Round 2
// 783.772 us; speedup vs baseline: 1.7371x; 1.7371x over previous
//
#include <hip/hip_runtime.h>

#define BB 32
#define LL 128
#define CC 1024
#define EE 256
#define NH 4
#define HD 64

typedef __attribute__((ext_vector_type(8))) short bf16x8;
typedef __attribute__((ext_vector_type(16))) float f32x16;

__device__ __forceinline__ void fma4(float4& a, float s, const float4 v) {
    a.x = fmaf(s, v.x, a.x); a.y = fmaf(s, v.y, a.y);
    a.z = fmaf(s, v.z, a.z); a.w = fmaf(s, v.w, a.w);
}

__device__ __forceinline__ ushort f2bf(float f) {
    unsigned u = __float_as_uint(f);
    unsigned r = (u + 0x7FFFu + ((u >> 16) & 1u)) >> 16;
    return (ushort)r;
}

// ---------------- K1: SE adaptive-avg-pool  y0[b,i] = mean of 128 contiguous floats
__global__ __launch_bounds__(256) void k_pool(const float* __restrict__ x,
                                              float* __restrict__ y0) {
    int t = threadIdx.x;
    int lane = t & 63;
    int v = blockIdx.x * 4 + (t >> 6);            // 0..32767  (b*1024 + i)
    const float2* p = (const float2*)(x + (size_t)v * 128);
    float2 d = p[lane];
    float s = d.x + d.y;
    #pragma unroll
    for (int m = 1; m < 64; m <<= 1) s += __shfl_xor(s, m, 64);
    if (lane == 0) y0[v] = s * (1.0f / 128.0f);
}

// ---------------- K2/K3: SE fc layers.  out[b,i] = act( sum_c in[b,c]*w[i,c] )
template <int ACT>   // 0 = relu, 1 = sigmoid
__global__ __launch_bounds__(256) void k_se_fc(const float* __restrict__ in,
                                               const float* __restrict__ w,
                                               float* __restrict__ outp) {
    __shared__ float yin[1024];
    int b = blockIdx.x >> 2;
    int it = blockIdx.x & 3;
    int t = threadIdx.x;
    for (int i = t; i < 1024; i += 256) yin[i] = in[b * 1024 + i];
    __syncthreads();
    int i = it * 256 + t;
    const float4* wr = (const float4*)(w + (size_t)i * 1024);
    float acc = 0.f;
    #pragma unroll 4
    for (int c4 = 0; c4 < 256; ++c4) {
        float4 wv = wr[c4];
        const float* yy = &yin[c4 * 4];
        acc += wv.x * yy[0] + wv.y * yy[1] + wv.z * yy[2] + wv.w * yy[3];
    }
    float r = (ACT == 0) ? fmaxf(acc, 0.f) : (1.f / (1.f + expf(-acc)));
    outp[b * 1024 + i] = r;
}

// ---------------- K4: fused SE-scale + 1x1 conv over L.
// xg[b,c,e] = sum_l ws[e,l] * x[b,l,c] * y[b, 8l + (c>>7)]
__global__ __launch_bounds__(256) void k_conv(const float* __restrict__ x,
                                              const float* __restrict__ wsi,
                                              const float* __restrict__ y,
                                              float* __restrict__ xg) {
    __shared__ __align__(16) float wsT[32 * 260];   // [l' in chunk][e], pad 260
    __shared__ __align__(16) float xl[32 * 32];     // [l'][c]
    __shared__ float sl[128];
    int b = blockIdx.x >> 5, ct = blockIdx.x & 31;
    int c0 = ct * 32;
    int t = threadIdx.x;
    if (t < 128) sl[t] = y[b * 1024 + 8 * t + (c0 >> 7)];
    int e4 = (t & 63) * 4, cq = t >> 6;
    float acc[4][8];
    #pragma unroll
    for (int i = 0; i < 4; ++i)
        #pragma unroll
        for (int j = 0; j < 8; ++j) acc[i][j] = 0.f;

    for (int lc = 0; lc < 4; ++lc) {
        __syncthreads();
        for (int idx = t; idx < 8192; idx += 256) {      // ws chunk [32 l'][256 e] transposed
            int e = idx >> 5, lp = idx & 31;
            wsT[lp * 260 + e] = wsi[e * 128 + lc * 32 + lp];
        }
        {
            int c = t & 31, l0 = t >> 5;
            for (int lp = l0; lp < 32; lp += 8)
                xl[lp * 32 + c] = x[(size_t)b * 131072 + (size_t)(lc * 32 + lp) * 1024 + c0 + c];
        }
        __syncthreads();
        for (int lp = 0; lp < 32; ++lp) {
            float s = sl[lc * 32 + lp];
            float4 wv = *(const float4*)&wsT[lp * 260 + e4];
            float4 x0 = *(const float4*)&xl[lp * 32 + cq * 8];
            float4 x1 = *(const float4*)&xl[lp * 32 + cq * 8 + 4];
            float w0 = wv.x * s, w1 = wv.y * s, w2 = wv.z * s, w3 = wv.w * s;
            float xc[8] = {x0.x, x0.y, x0.z, x0.w, x1.x, x1.y, x1.z, x1.w};
            #pragma unroll
            for (int ci = 0; ci < 8; ++ci) {
                acc[0][ci] = fmaf(w0, xc[ci], acc[0][ci]);
                acc[1][ci] = fmaf(w1, xc[ci], acc[1][ci]);
                acc[2][ci] = fmaf(w2, xc[ci], acc[2][ci]);
                acc[3][ci] = fmaf(w3, xc[ci], acc[3][ci]);
            }
        }
    }
    size_t base = (size_t)b * CC * EE;
    #pragma unroll
    for (int ci = 0; ci < 8; ++ci) {
        int c = c0 + cq * 8 + ci;
        float4 o = make_float4(acc[0][ci], acc[1][ci], acc[2][ci], acc[3][ci]);
        *(float4*)&xg[base + (size_t)c * EE + e4] = o;
    }
}

// ---------------- K5: packed q,k projection (v skipped), bf16 output.
// qk[bc, col] = bf16( bias[col] + sum_e' xg[bc,e'] * W[col,e'] ),  col in [0,512)
__global__ __launch_bounds__(256) void k_qkv(const float* __restrict__ xg,
                                             const float* __restrict__ W,
                                             const float* __restrict__ bias,
                                             ushort* __restrict__ qk) {
    __shared__ __align__(16) float Al[64 * 64];   // [kk][m] xor-swizzled
    __shared__ __align__(16) float Bl[64 * 64];   // [kk][n] xor-swizzled
    int rt = blockIdx.x >> 3, ct = blockIdx.x & 7;
    int row0 = rt * 64, col0 = ct * 64;
    int t = threadIdx.x, tx = t & 15, ty = t >> 4;
    float4 acc[4];
    acc[0] = acc[1] = acc[2] = acc[3] = make_float4(0, 0, 0, 0);
    int k4 = (t & 15) * 4, rr0 = t >> 4;
    for (int kt = 0; kt < 4; ++kt) {
        for (int rr = rr0; rr < 64; rr += 16) {
            float4 v = *(const float4*)&xg[(size_t)(row0 + rr) * EE + kt * 64 + k4];
            float vv[4] = {v.x, v.y, v.z, v.w};
            float4 w = *(const float4*)&W[(size_t)(col0 + rr) * EE + kt * 64 + k4];
            float ww[4] = {w.x, w.y, w.z, w.w};
            #pragma unroll
            for (int i = 0; i < 4; ++i) {
                int kk = k4 + i;
                int idx = kk * 64 + (((((rr >> 2) ^ (kk >> 2)) & 15) << 2) | (rr & 3));
                Al[idx] = vv[i];
                Bl[idx] = ww[i];
            }
        }
        __syncthreads();
        #pragma unroll 8
        for (int kk = 0; kk < 64; ++kk) {
            int s4 = (kk >> 2) & 15;
            float4 a = *(const float4*)&Al[kk * 64 + (((ty ^ s4) & 15) << 2)];
            float4 bv = *(const float4*)&Bl[kk * 64 + (((tx ^ s4) & 15) << 2)];
            fma4(acc[0], a.x, bv); fma4(acc[1], a.y, bv);
            fma4(acc[2], a.z, bv); fma4(acc[3], a.w, bv);
        }
        __syncthreads();
    }
    float4 bb = *(const float4*)&bias[col0 + tx * 4];
    #pragma unroll
    for (int i = 0; i < 4; ++i) {
        float4 v = acc[i];
        v.x += bb.x; v.y += bb.y; v.z += bb.z; v.w += bb.w;
        ushort4 o = make_ushort4(f2bf(v.x), f2bf(v.y), f2bf(v.z), f2bf(v.w));
        *(ushort4*)&qk[(size_t)(row0 + ty * 4 + i) * 512 + col0 + tx * 4] = o;
    }
}

// ---------------- K6: b_adj = mean_h softmax(q_h k_h^T / 8) via bf16 MFMA.
// Grid 256: block = (b, 128 q-rows), 4 waves; wave = 32 q-rows, all 4 heads.
// Two passes: (1) exp-rowsums, (2) recompute + normalize + write.
__global__ __launch_bounds__(256, 1) void k_attn(const ushort* __restrict__ qkb,
                                                 float* __restrict__ badj) {
    __shared__ __align__(16) ushort klds[2][32 * 256];   // [buf][key][d swizzled]
    const float SCL2 = 0.18033688011112042f;             // log2(e)/8
    int bid = blockIdx.x;
    int b = bid & 31, qt = bid >> 5;          // same-b blocks share bid%8 -> same XCD
    int t = threadIdx.x, g = t >> 6, l = t & 63;
    int col = l & 31, hi = l >> 5;
    size_t qbase = (size_t)b * 1024 * 512;
    int qrow = qt * 128 + g * 32 + col;

    // A fragments: qa[h][kk], lane holds q[row=col][d = h*64+kk*16+hi*8 ..+8]
    bf16x8 qa[4][4];
    #pragma unroll
    for (int h = 0; h < 4; ++h)
        #pragma unroll
        for (int kk = 0; kk < 4; ++kk)
            qa[h][kk] = *(const bf16x8*)&qkb[qbase + (size_t)qrow * 512 + h * 64 + kk * 16 + hi * 8];

    // staging: thread t handles key=t>>3, dblk = (t&7)+8j, j=0..3 (16B chunks)
    int skey = t >> 3, sd = t & 7;
    const ushort* kg = qkb + qbase + 256 + sd * 8;
    int swbase = skey * 256 + ((sd ^ (skey & 7)) << 3);

    float prsum[4][16];
    #pragma unroll
    for (int h = 0; h < 4; ++h)
        #pragma unroll
        for (int r = 0; r < 16; ++r) prsum[h][r] = 0.f;

    // ---------- pass 1 ----------
    {
        bf16x8 st[4];
        #pragma unroll
        for (int j = 0; j < 4; ++j) st[j] = *(const bf16x8*)&kg[(size_t)skey * 512 + j * 64];
        #pragma unroll
        for (int j = 0; j < 4; ++j) *(bf16x8*)&klds[0][swbase + j * 64] = st[j];
    }
    __syncthreads();
    for (int kt = 0; kt < 32; ++kt) {
        bf16x8 nx[4];
        if (kt < 31) {
            #pragma unroll
            for (int j = 0; j < 4; ++j)
                nx[j] = *(const bf16x8*)&kg[(size_t)((kt + 1) * 32 + skey) * 512 + j * 64];
        }
        const ushort* kl = &klds[kt & 1][0];
        f32x16 acc[4];
        #pragma unroll
        for (int h = 0; h < 4; ++h)
            #pragma unroll
            for (int r = 0; r < 16; ++r) acc[h][r] = 0.f;
        #pragma unroll
        for (int kk = 0; kk < 4; ++kk) {
            #pragma unroll
            for (int h = 0; h < 4; ++h) {
                bf16x8 kb = *(const bf16x8*)&kl[col * 256 + (h * 8 + ((kk * 2 + hi) ^ (col & 7))) * 8];
                acc[h] = __builtin_amdgcn_mfma_f32_32x32x16_bf16(qa[h][kk], kb, acc[h], 0, 0, 0);
            }
        }
        #pragma unroll
        for (int h = 0; h < 4; ++h)
            #pragma unroll
            for (int r = 0; r < 16; ++r)
                prsum[h][r] += exp2f(acc[h][r] * SCL2);
        if (kt < 31) {
            #pragma unroll
            for (int j = 0; j < 4; ++j) *(bf16x8*)&klds[(kt + 1) & 1][swbase + j * 64] = nx[j];
        }
        __syncthreads();
    }
    // reduce over the 32 key-columns (lane bits 0..4), then invert (fold 1/4 head avg)
    #pragma unroll
    for (int h = 0; h < 4; ++h)
        #pragma unroll
        for (int r = 0; r < 16; ++r) {
            float s = prsum[h][r];
            s += __shfl_xor(s, 1, 64);
            s += __shfl_xor(s, 2, 64);
            s += __shfl_xor(s, 4, 64);
            s += __shfl_xor(s, 8, 64);
            s += __shfl_xor(s, 16, 64);
            prsum[h][r] = 0.25f / s;
        }

    // ---------- pass 2 ----------
    {
        bf16x8 st[4];
        #pragma unroll
        for (int j = 0; j < 4; ++j) st[j] = *(const bf16x8*)&kg[(size_t)skey * 512 + j * 64];
        #pragma unroll
        for (int j = 0; j < 4; ++j) *(bf16x8*)&klds[0][swbase + j * 64] = st[j];
    }
    __syncthreads();
    float* orow = badj + (size_t)b * 1048576 + (size_t)(qt * 128 + g * 32) * 1024;
    for (int kt = 0; kt < 32; ++kt) {
        bf16x8 nx[4];
        if (kt < 31) {
            #pragma unroll
            for (int j = 0; j < 4; ++j)
                nx[j] = *(const bf16x8*)&kg[(size_t)((kt + 1) * 32 + skey) * 512 + j * 64];
        }
        const ushort* kl = &klds[kt & 1][0];
        f32x16 acc[4];
        #pragma unroll
        for (int h = 0; h < 4; ++h)
            #pragma unroll
            for (int r = 0; r < 16; ++r) acc[h][r] = 0.f;
        #pragma unroll
        for (int kk = 0; kk < 4; ++kk) {
            #pragma unroll
            for (int h = 0; h < 4; ++h) {
                bf16x8 kb = *(const bf16x8*)&kl[col * 256 + (h * 8 + ((kk * 2 + hi) ^ (col & 7))) * 8];
                acc[h] = __builtin_amdgcn_mfma_f32_32x32x16_bf16(qa[h][kk], kb, acc[h], 0, 0, 0);
            }
        }
        #pragma unroll
        for (int r = 0; r < 16; ++r) {
            float v = exp2f(acc[0][r] * SCL2) * prsum[0][r] +
                      exp2f(acc[1][r] * SCL2) * prsum[1][r] +
                      exp2f(acc[2][r] * SCL2) * prsum[2][r] +
                      exp2f(acc[3][r] * SCL2) * prsum[3][r];
            int row = (r & 3) + 8 * (r >> 2) + 4 * hi;
            orow[(size_t)row * 1024 + kt * 32 + col] = v;
        }
        if (kt < 31) {
            #pragma unroll
            for (int j = 0; j < 4; ++j) *(bf16x8*)&klds[(kt + 1) & 1][swbase + j * 64] = nx[j];
        }
        __syncthreads();
    }
}

// ---------------- K6b: bxg = b_adj @ xg   (per b: [1024x1024]@[1024x256])
__global__ __launch_bounds__(256) void k_badjxg(const float* __restrict__ badj,
                                                const float* __restrict__ xg,
                                                float* __restrict__ bxg) {
    __shared__ __align__(16) float Al[64 * 64];   // [kk][m] swizzled
    __shared__ __align__(16) float Bl[64 * 68];   // [kk][n] straight, pad 68
    int bb = blockIdx.x >> 6;
    int mt = (blockIdx.x >> 2) & 15, nt = blockIdx.x & 3;
    int m0 = mt * 64, n0 = nt * 64;
    int t = threadIdx.x, tx = t & 15, ty = t >> 4;
    float4 acc[4];
    acc[0] = acc[1] = acc[2] = acc[3] = make_float4(0, 0, 0, 0);
    int k4 = (t & 15) * 4, rr0 = t >> 4;
    for (int kt = 0; kt < 16; ++kt) {
        for (int rr = rr0; rr < 64; rr += 16) {
            float4 v = *(const float4*)&badj[(size_t)bb * 1048576 + (size_t)(m0 + rr) * 1024 + kt * 64 + k4];
            float vv[4] = {v.x, v.y, v.z, v.w};
            #pragma unroll
            for (int i = 0; i < 4; ++i) {
                int kk = k4 + i;
                Al[kk * 64 + (((((rr >> 2) ^ (kk >> 2)) & 15) << 2) | (rr & 3))] = vv[i];
            }
        }
        {
            int n4 = (t & 15) * 4, kk0 = t >> 4;
            for (int kk = kk0; kk < 64; kk += 16)
                *(float4*)&Bl[kk * 68 + n4] =
                    *(const float4*)&xg[(size_t)(bb * 1024 + kt * 64 + kk) * EE + n0 + n4];
        }
        __syncthreads();
        #pragma unroll 8
        for (int kk = 0; kk < 64; ++kk) {
            int s4 = (kk >> 2) & 15;
            float4 a = *(const float4*)&Al[kk * 64 + (((ty ^ s4) & 15) << 2)];
            float4 bv = *(const float4*)&Bl[kk * 68 + tx * 4];
            fma4(acc[0], a.x, bv); fma4(acc[1], a.y, bv);
            fma4(acc[2], a.z, bv); fma4(acc[3], a.w, bv);
        }
        __syncthreads();
    }
    #pragma unroll
    for (int i = 0; i < 4; ++i)
        *(float4*)&bxg[(size_t)(bb * 1024 + m0 + ty * 4 + i) * EE + n0 + tx * 4] = acc[i];
}

// ---------------- K7: cheb = xg@theta0 + bxg@theta1   ([B,1024,256])
__global__ __launch_bounds__(256) void k_cheb(const float* __restrict__ xg,
                                              const float* __restrict__ bxg,
                                              const float* __restrict__ theta,
                                              float* __restrict__ cheb) {
    __shared__ __align__(16) float Al[64 * 64];
    __shared__ __align__(16) float Bl[64 * 68];
    int bb = blockIdx.x >> 6;
    int mt = (blockIdx.x >> 2) & 15, nt = blockIdx.x & 3;
    int m0 = mt * 64, n0 = nt * 64;
    int t = threadIdx.x, tx = t & 15, ty = t >> 4;
    float4 acc[4];
    acc[0] = acc[1] = acc[2] = acc[3] = make_float4(0, 0, 0, 0);
    int k4 = (t & 15) * 4, rr0 = t >> 4;
    for (int ph = 0; ph < 2; ++ph) {
        const float* A = ph ? bxg : xg;
        const float* Bm = theta + (size_t)ph * 65536;
        for (int kt = 0; kt < 4; ++kt) {
            for (int rr = rr0; rr < 64; rr += 16) {
                float4 v = *(const float4*)&A[(size_t)(bb * 1024 + m0 + rr) * EE + kt * 64 + k4];
                float vv[4] = {v.x, v.y, v.z, v.w};
                #pragma unroll
                for (int i = 0; i < 4; ++i) {
                    int kk = k4 + i;
                    Al[kk * 64 + (((((rr >> 2) ^ (kk >> 2)) & 15) << 2) | (rr & 3))] = vv[i];
                }
            }
            {
                int n4 = (t & 15) * 4, kk0 = t >> 4;
                for (int kk = kk0; kk < 64; kk += 16)
                    *(float4*)&Bl[kk * 68 + n4] =
                        *(const float4*)&Bm[(size_t)(kt * 64 + kk) * EE + n0 + n4];
            }
            __syncthreads();
            #pragma unroll 8
            for (int kk = 0; kk < 64; ++kk) {
                int s4 = (kk >> 2) & 15;
                float4 a = *(const float4*)&Al[kk * 64 + (((ty ^ s4) & 15) << 2)];
                float4 bv = *(const float4*)&Bl[kk * 68 + tx * 4];
                fma4(acc[0], a.x, bv); fma4(acc[1], a.y, bv);
                fma4(acc[2], a.z, bv); fma4(acc[3], a.w, bv);
            }
            __syncthreads();
        }
    }
    #pragma unroll
    for (int i = 0; i < 4; ++i)
        *(float4*)&cheb[(size_t)(bb * 1024 + m0 + ty * 4 + i) * EE + n0 + tx * 4] = acc[i];
}

// ---------------- K8: out[b,e,c] = relu( xg[b,c,e] + relu(cheb[b, 4e+(c>>8), c&255]) )
__global__ __launch_bounds__(256) void k_final(const float* __restrict__ xg,
                                               const float* __restrict__ cheb,
                                               float* __restrict__ outp) {
    __shared__ float xl[256 * 33];
    int b = blockIdx.x >> 5;
    int et = (blockIdx.x >> 2) & 7, cb = blockIdx.x & 3;
    int e0 = et * 32, c0 = cb * 256;
    int t = threadIdx.x;
    {
        int e = t & 31, cl0 = t >> 5;
        for (int c = cl0; c < 256; c += 8)
            xl[c * 33 + e] = xg[((size_t)b * 1024 + c0 + c) * EE + e0 + e];
    }
    __syncthreads();
    int q4 = c0 >> 8;
    for (int el = 0; el < 32; ++el) {
        int e = e0 + el;
        float ch = cheb[((size_t)b * 1024 + e * 4 + q4) * EE + t];
        float v = fmaxf(ch, 0.f);
        float xin = xl[t * 33 + el];
        outp[((size_t)b * 256 + e) * 1024 + c0 + t] = fmaxf(xin + v, 0.f);
    }
}

extern "C" void kernel_launch(void* const* d_in, const int* in_sizes, int n_in,
                              void* d_out, int out_size, void* d_ws, size_t ws_size,
                              hipStream_t stream) {
    const float* x     = (const float*)d_in[0];
    const float* w1    = (const float*)d_in[1];
    const float* w2    = (const float*)d_in[2];
    const float* wsi   = (const float*)d_in[3];
    const float* wqkv  = (const float*)d_in[4];
    const float* bqkv  = (const float*)d_in[5];
    const float* theta = (const float*)d_in[6];

    float* out  = (float*)d_out;
    float* badj = out + (size_t)BB * EE * CC;      // second output, 32*1024*1024

    // workspace layout (floats), total 128 MiB:
    //   xg   [B,C,E]        @ 0          (8,388,608 f)
    //   qk   [B*C,512] bf16 @ 8,388,608  (occupies 8,388,608 f worth of bytes)
    //        cheb (fp32, 8,388,608 f) aliases this region after attn is done
    //   bxg  [B,C,E]        @ 25,165,824 (8,388,608 f)
    //   SE buffers alias the (not yet written) qk region.
    float* wsf  = (float*)d_ws;
    float* xg   = wsf;
    ushort* qk  = (ushort*)(wsf + 8388608);
    float* cheb = wsf + 8388608;
    float* bxg  = wsf + 25165824;
    float* y0   = wsf + 8388608;       // B*C, dead before k_qkv writes qk
    float* hh   = y0 + 32768;
    float* yy   = y0 + 65536;

    k_pool   <<<8192, 256, 0, stream>>>(x, y0);
    k_se_fc<0><<<128, 256, 0, stream>>>(y0, w1, hh);
    k_se_fc<1><<<128, 256, 0, stream>>>(hh, w2, yy);
    k_conv   <<<1024, 256, 0, stream>>>(x, wsi, yy, xg);
    k_qkv    <<<4096, 256, 0, stream>>>(xg, wqkv, bqkv, qk);
    k_attn   <<<256,  256, 0, stream>>>(qk, badj);
    k_badjxg <<<2048, 256, 0, stream>>>(badj, xg, bxg);
    k_cheb   <<<2048, 256, 0, stream>>>(xg, bxg, theta, cheb);
    k_final  <<<1024, 256, 0, stream>>>(xg, cheb, out);
}

// Round 3
// 365.037 us; speedup vs baseline: 3.7297x; 2.1471x over previous
//
#include <hip/hip_runtime.h>

#define BB 32
#define CC 1024
#define EE 256

typedef __attribute__((ext_vector_type(8))) short bf16x8;
typedef __attribute__((ext_vector_type(16))) float f32x16;

__device__ __forceinline__ ushort f2bf(float f) {
    unsigned u = __float_as_uint(f);
    unsigned r = (u + 0x7FFFu + ((u >> 16) & 1u)) >> 16;
    return (ushort)r;
}
__device__ __forceinline__ float bf2f(ushort u) { return __uint_as_float((unsigned)u << 16); }

// stage 128 rows x 64 bf16 (128B) from global into 16KB LDS, source pre-swizzled so that
// ds_read with chunk ^= (row&7) returns linear data. LDS dest must be wave-uniform.
__device__ __forceinline__ void stage16(const char* srcBase, long stride, ushort* ldsBase,
                                        int wid, int lane) {
    #pragma unroll
    for (int i = 0; i < 4; ++i) {
        int gch = (wid * 4 + i) * 64 + lane;
        int row = gch >> 3, cj = gch & 7;
        const char* src = srcBase + (long)row * stride + ((cj ^ (row & 7)) << 4);
        __builtin_amdgcn_global_load_lds(
            (const __attribute__((address_space(1))) unsigned*)src,
            (__attribute__((address_space(3))) unsigned*)(ldsBase + (wid * 4 + i) * 512),
            16, 0, 0);
    }
}

__device__ __forceinline__ bf16x8 frag(const ushort* L, int row, int kc) {
    return *(const bf16x8*)&L[row * 64 + ((kc ^ (row & 7)) << 3)];
}

// ---------------- K1: SE adaptive-avg-pool
__global__ __launch_bounds__(256) void k_pool(const float* __restrict__ x,
                                              float* __restrict__ y0) {
    int t = threadIdx.x;
    int lane = t & 63;
    int v = blockIdx.x * 4 + (t >> 6);
    const float2* p = (const float2*)(x + (size_t)v * 128);
    float2 d = p[lane];
    float s = d.x + d.y;
    #pragma unroll
    for (int m = 1; m < 64; m <<= 1) s += __shfl_xor(s, m, 64);
    if (lane == 0) y0[v] = s * (1.0f / 128.0f);
}

// ---------------- K2/K3: SE fc layers
template <int ACT>
__global__ __launch_bounds__(256) void k_se_fc(const float* __restrict__ in,
                                               const float* __restrict__ w,
                                               float* __restrict__ outp) {
    __shared__ float yin[1024];
    int b = blockIdx.x >> 2;
    int it = blockIdx.x & 3;
    int t = threadIdx.x;
    for (int i = t; i < 1024; i += 256) yin[i] = in[b * 1024 + i];
    __syncthreads();
    int i = it * 256 + t;
    const float4* wr = (const float4*)(w + (size_t)i * 1024);
    float acc = 0.f;
    #pragma unroll 4
    for (int c4 = 0; c4 < 256; ++c4) {
        float4 wv = wr[c4];
        const float* yy = &yin[c4 * 4];
        acc += wv.x * yy[0] + wv.y * yy[1] + wv.z * yy[2] + wv.w * yy[3];
    }
    float r = (ACT == 0) ? fmaxf(acc, 0.f) : (1.f / (1.f + expf(-acc)));
    outp[b * 1024 + i] = r;
}

// ---------------- K4: fused SE-scale + 1x1 conv, bf16 output
__global__ __launch_bounds__(256) void k_conv(const float* __restrict__ x,
                                              const float* __restrict__ wsi,
                                              const float* __restrict__ y,
                                              ushort* __restrict__ xgb) {
    __shared__ __align__(16) float wsT[32 * 260];
    __shared__ __align__(16) float xl[32 * 32];
    __shared__ float sl[128];
    int b = blockIdx.x >> 5, ct = blockIdx.x & 31;
    int c0 = ct * 32;
    int t = threadIdx.x;
    if (t < 128) sl[t] = y[b * 1024 + 8 * t + (c0 >> 7)];
    int e4 = (t & 63) * 4, cq = t >> 6;
    float acc[4][8];
    #pragma unroll
    for (int i = 0; i < 4; ++i)
        #pragma unroll
        for (int j = 0; j < 8; ++j) acc[i][j] = 0.f;

    for (int lc = 0; lc < 4; ++lc) {
        __syncthreads();
        for (int idx = t; idx < 8192; idx += 256) {
            int e = idx >> 5, lp = idx & 31;
            wsT[lp * 260 + e] = wsi[e * 128 + lc * 32 + lp];
        }
        {
            int c = t & 31, l0 = t >> 5;
            for (int lp = l0; lp < 32; lp += 8)
                xl[lp * 32 + c] = x[(size_t)b * 131072 + (size_t)(lc * 32 + lp) * 1024 + c0 + c];
        }
        __syncthreads();
        for (int lp = 0; lp < 32; ++lp) {
            float s = sl[lc * 32 + lp];
            float4 wv = *(const float4*)&wsT[lp * 260 + e4];
            float4 x0 = *(const float4*)&xl[lp * 32 + cq * 8];
            float4 x1 = *(const float4*)&xl[lp * 32 + cq * 8 + 4];
            float w0 = wv.x * s, w1 = wv.y * s, w2 = wv.z * s, w3 = wv.w * s;
            float xc[8] = {x0.x, x0.y, x0.z, x0.w, x1.x, x1.y, x1.z, x1.w};
            #pragma unroll
            for (int ci = 0; ci < 8; ++ci) {
                acc[0][ci] = fmaf(w0, xc[ci], acc[0][ci]);
                acc[1][ci] = fmaf(w1, xc[ci], acc[1][ci]);
                acc[2][ci] = fmaf(w2, xc[ci], acc[2][ci]);
                acc[3][ci] = fmaf(w3, xc[ci], acc[3][ci]);
            }
        }
    }
    size_t base = (size_t)b * CC * EE;
    #pragma unroll
    for (int ci = 0; ci < 8; ++ci) {
        int c = c0 + cq * 8 + ci;
        *(ushort4*)&xgb[base + (size_t)c * EE + e4] =
            make_ushort4(f2bf(acc[0][ci]), f2bf(acc[1][ci]), f2bf(acc[2][ci]), f2bf(acc[3][ci]));
    }
}

// ---------------- K-prep: Wcat [1024][256] bf16 = [Wq; Wk; theta0^T; theta1^T]
__global__ __launch_bounds__(256) void k_prep(const float* __restrict__ W,
                                              const float* __restrict__ theta,
                                              ushort* __restrict__ Wcat) {
    int idx = blockIdx.x * 256 + threadIdx.x;
    int n = idx >> 8, k = idx & 255;
    float v;
    if (n < 512) v = W[n * 256 + k];
    else if (n < 768) v = theta[k * 256 + (n - 512)];
    else v = theta[65536 + k * 256 + (n - 768)];
    Wcat[idx] = f2bf(v);
}

// ---------------- K5: unified projection GEMM.
// out[m, n] = sum_k xg[m,k] * Wcat[n,k];  n<512 -> qk (+bias), 512..767 -> xt0, 768..1023 -> xt1T
__global__ __launch_bounds__(256) void k_mm1(const ushort* __restrict__ xgb,
                                             const ushort* __restrict__ Wcat,
                                             const float* __restrict__ bias,
                                             ushort* __restrict__ qk,
                                             ushort* __restrict__ xt0,
                                             ushort* __restrict__ xt1T) {
    __shared__ __align__(16) ushort smem[32768];   // 2 bufs x (Al 8192 + Bl 8192)
    // XCD remap: all 8 n-tiles of an m-strip on one XCD (A-strip L2 reuse)
    int d = blockIdx.x;
    int xcd = d & 7, r = d >> 3;
    int mt = xcd * 32 + (r >> 3), nt = r & 7;
    int m0 = mt * 128, n0 = nt * 128;
    int t = threadIdx.x, wid = t >> 6, l = t & 63;
    int ln = l & 31, hi = l >> 5;
    int wr = wid >> 1, wc = wid & 1;
    const char* Ab = (const char*)xgb + (size_t)m0 * 512;
    const char* Bb = (const char*)Wcat + (size_t)n0 * 512;
    f32x16 acc[2][2];
    #pragma unroll
    for (int i = 0; i < 2; ++i)
        #pragma unroll
        for (int j = 0; j < 2; ++j)
            #pragma unroll
            for (int q = 0; q < 16; ++q) acc[i][j][q] = 0.f;

    stage16(Ab, 512, smem, wid, l);
    stage16(Bb, 512, smem + 8192, wid, l);
    __syncthreads();
    for (int kt = 0; kt < 4; ++kt) {
        const ushort* Al = smem + (kt & 1) * 16384;
        const ushort* Bl = Al + 8192;
        if (kt < 3) {
            ushort* nb = smem + ((kt + 1) & 1) * 16384;
            stage16(Ab + (kt + 1) * 128, 512, nb, wid, l);
            stage16(Bb + (kt + 1) * 128, 512, nb + 8192, wid, l);
        }
        #pragma unroll
        for (int ks = 0; ks < 4; ++ks) {
            int kc = ks * 2 + hi;
            int mr = wr * 64 + ln, nr = wc * 64 + ln;
            bf16x8 a0 = frag(Al, mr, kc);
            bf16x8 a1 = frag(Al, mr + 32, kc);
            bf16x8 b0 = frag(Bl, nr, kc);
            bf16x8 b1 = frag(Bl, nr + 32, kc);
            acc[0][0] = __builtin_amdgcn_mfma_f32_32x32x16_bf16(a0, b0, acc[0][0], 0, 0, 0);
            acc[0][1] = __builtin_amdgcn_mfma_f32_32x32x16_bf16(a0, b1, acc[0][1], 0, 0, 0);
            acc[1][0] = __builtin_amdgcn_mfma_f32_32x32x16_bf16(a1, b0, acc[1][0], 0, 0, 0);
            acc[1][1] = __builtin_amdgcn_mfma_f32_32x32x16_bf16(a1, b1, acc[1][1], 0, 0, 0);
        }
        __syncthreads();
    }
    if (nt < 6) {
        float bv[2] = {0.f, 0.f};
        if (nt < 4) {
            bv[0] = bias[nt * 128 + wc * 64 + ln];
            bv[1] = bias[nt * 128 + wc * 64 + 32 + ln];
        }
        #pragma unroll
        for (int mi = 0; mi < 2; ++mi)
            #pragma unroll
            for (int ni = 0; ni < 2; ++ni) {
                int ncol = wc * 64 + ni * 32 + ln;
                #pragma unroll
                for (int r2 = 0; r2 < 4; ++r2)
                    #pragma unroll
                    for (int j = 0; j < 4; ++j) {
                        int mloc = wr * 64 + mi * 32 + 8 * r2 + 4 * hi + j;
                        float v = acc[mi][ni][r2 * 4 + j] + bv[ni];
                        size_t m = (size_t)(m0 + mloc);
                        if (nt < 4) qk[m * 512 + nt * 128 + ncol] = f2bf(v);
                        else        xt0[m * 256 + (nt - 4) * 128 + ncol] = f2bf(v);
                    }
            }
    } else {
        // transpose through LDS, write xt1T[b][n][k=1024]
        ushort* Tl = smem;   // [128][136]
        #pragma unroll
        for (int mi = 0; mi < 2; ++mi)
            #pragma unroll
            for (int ni = 0; ni < 2; ++ni) {
                int nl = wc * 64 + ni * 32 + ln;
                #pragma unroll
                for (int r2 = 0; r2 < 4; ++r2) {
                    int mbase = wr * 64 + mi * 32 + 8 * r2 + 4 * hi;
                    ushort4 pk = make_ushort4(f2bf(acc[mi][ni][r2 * 4 + 0]),
                                              f2bf(acc[mi][ni][r2 * 4 + 1]),
                                              f2bf(acc[mi][ni][r2 * 4 + 2]),
                                              f2bf(acc[mi][ni][r2 * 4 + 3]));
                    *(ushort4*)&Tl[nl * 136 + mbase] = pk;
                }
            }
        __syncthreads();
        int n = t >> 1, mh = (t & 1) * 64;
        int bq = m0 >> 10, mib = m0 & 1023;
        ushort* dst = xt1T + (((size_t)(bq * 256 + (nt - 6) * 128 + n)) << 10) + mib + mh;
        #pragma unroll
        for (int j = 0; j < 8; ++j)
            *(uint4*)(dst + j * 8) = *(const uint4*)&Tl[n * 136 + mh + j * 8];
    }
}

// ---------------- K6: b_adj = mean_h softmax(q k^T / 8) via bf16 MFMA (unchanged)
__global__ __launch_bounds__(256, 1) void k_attn(const ushort* __restrict__ qkb,
                                                 float* __restrict__ badj) {
    __shared__ __align__(16) ushort klds[2][32 * 256];
    const float SCL2 = 0.18033688011112042f;
    int bid = blockIdx.x;
    int b = bid & 31, qt = bid >> 5;
    int t = threadIdx.x, g = t >> 6, l = t & 63;
    int col = l & 31, hi = l >> 5;
    size_t qbase = (size_t)b * 1024 * 512;
    int qrow = qt * 128 + g * 32 + col;

    bf16x8 qa[4][4];
    #pragma unroll
    for (int h = 0; h < 4; ++h)
        #pragma unroll
        for (int kk = 0; kk < 4; ++kk)
            qa[h][kk] = *(const bf16x8*)&qkb[qbase + (size_t)qrow * 512 + h * 64 + kk * 16 + hi * 8];

    int skey = t >> 3, sd = t & 7;
    const ushort* kg = qkb + qbase + 256 + sd * 8;
    int swbase = skey * 256 + ((sd ^ (skey & 7)) << 3);

    float prsum[4][16];
    #pragma unroll
    for (int h = 0; h < 4; ++h)
        #pragma unroll
        for (int r = 0; r < 16; ++r) prsum[h][r] = 0.f;

    {
        bf16x8 st[4];
        #pragma unroll
        for (int j = 0; j < 4; ++j) st[j] = *(const bf16x8*)&kg[(size_t)skey * 512 + j * 64];
        #pragma unroll
        for (int j = 0; j < 4; ++j) *(bf16x8*)&klds[0][swbase + j * 64] = st[j];
    }
    __syncthreads();
    for (int kt = 0; kt < 32; ++kt) {
        bf16x8 nx[4];
        if (kt < 31) {
            #pragma unroll
            for (int j = 0; j < 4; ++j)
                nx[j] = *(const bf16x8*)&kg[(size_t)((kt + 1) * 32 + skey) * 512 + j * 64];
        }
        const ushort* kl = &klds[kt & 1][0];
        f32x16 acc[4];
        #pragma unroll
        for (int h = 0; h < 4; ++h)
            #pragma unroll
            for (int r = 0; r < 16; ++r) acc[h][r] = 0.f;
        #pragma unroll
        for (int kk = 0; kk < 4; ++kk) {
            #pragma unroll
            for (int h = 0; h < 4; ++h) {
                bf16x8 kb = *(const bf16x8*)&kl[col * 256 + (h * 8 + ((kk * 2 + hi) ^ (col & 7))) * 8];
                acc[h] = __builtin_amdgcn_mfma_f32_32x32x16_bf16(qa[h][kk], kb, acc[h], 0, 0, 0);
            }
        }
        #pragma unroll
        for (int h = 0; h < 4; ++h)
            #pragma unroll
            for (int r = 0; r < 16; ++r)
                prsum[h][r] += exp2f(acc[h][r] * SCL2);
        if (kt < 31) {
            #pragma unroll
            for (int j = 0; j < 4; ++j) *(bf16x8*)&klds[(kt + 1) & 1][swbase + j * 64] = nx[j];
        }
        __syncthreads();
    }
    #pragma unroll
    for (int h = 0; h < 4; ++h)
        #pragma unroll
        for (int r = 0; r < 16; ++r) {
            float s = prsum[h][r];
            s += __shfl_xor(s, 1, 64);
            s += __shfl_xor(s, 2, 64);
            s += __shfl_xor(s, 4, 64);
            s += __shfl_xor(s, 8, 64);
            s += __shfl_xor(s, 16, 64);
            prsum[h][r] = 0.25f / s;
        }

    {
        bf16x8 st[4];
        #pragma unroll
        for (int j = 0; j < 4; ++j) st[j] = *(const bf16x8*)&kg[(size_t)skey * 512 + j * 64];
        #pragma unroll
        for (int j = 0; j < 4; ++j) *(bf16x8*)&klds[0][swbase + j * 64] = st[j];
    }
    __syncthreads();
    float* orow = badj + (size_t)b * 1048576 + (size_t)(qt * 128 + g * 32) * 1024;
    for (int kt = 0; kt < 32; ++kt) {
        bf16x8 nx[4];
        if (kt < 31) {
            #pragma unroll
            for (int j = 0; j < 4; ++j)
                nx[j] = *(const bf16x8*)&kg[(size_t)((kt + 1) * 32 + skey) * 512 + j * 64];
        }
        const ushort* kl = &klds[kt & 1][0];
        f32x16 acc[4];
        #pragma unroll
        for (int h = 0; h < 4; ++h)
            #pragma unroll
            for (int r = 0; r < 16; ++r) acc[h][r] = 0.f;
        #pragma unroll
        for (int kk = 0; kk < 4; ++kk) {
            #pragma unroll
            for (int h = 0; h < 4; ++h) {
                bf16x8 kb = *(const bf16x8*)&kl[col * 256 + (h * 8 + ((kk * 2 + hi) ^ (col & 7))) * 8];
                acc[h] = __builtin_amdgcn_mfma_f32_32x32x16_bf16(qa[h][kk], kb, acc[h], 0, 0, 0);
            }
        }
        #pragma unroll
        for (int r = 0; r < 16; ++r) {
            float v = exp2f(acc[0][r] * SCL2) * prsum[0][r] +
                      exp2f(acc[1][r] * SCL2) * prsum[1][r] +
                      exp2f(acc[2][r] * SCL2) * prsum[2][r] +
                      exp2f(acc[3][r] * SCL2) * prsum[3][r];
            int row = (r & 3) + 8 * (r >> 2) + 4 * hi;
            orow[(size_t)row * 1024 + kt * 32 + col] = v;
        }
        if (kt < 31) {
            #pragma unroll
            for (int j = 0; j < 4; ++j) *(bf16x8*)&klds[(kt + 1) & 1][swbase + j * 64] = nx[j];
        }
        __syncthreads();
    }
}

// ---------------- K7: cheb = xt0 + badj @ xt1   (A: fp32 inline-converted, B: xt1T bf16)
__global__ __launch_bounds__(256) void k_mm2(const float* __restrict__ badj,
                                             const ushort* __restrict__ xt1T,
                                             const ushort* __restrict__ xt0,
                                             ushort* __restrict__ cheb) {
    __shared__ __align__(16) ushort smem[32768];
    // XCD remap: n-tile pair of same (b,mt) on one XCD
    int d = blockIdx.x;
    int xcd = d & 7, r = d >> 3;
    int lin = xcd * 64 + r;
    int b = lin >> 4, mt = (lin >> 1) & 7, nt = lin & 1;
    int m0 = mt * 128, n0 = nt * 128;
    int t = threadIdx.x, wid = t >> 6, l = t & 63;
    int ln = l & 31, hi = l >> 5;
    int wr = wid >> 1, wc = wid & 1;
    const float* Ab = badj + ((size_t)b << 20) + (size_t)m0 * 1024;
    const char* Bb = (const char*)xt1T + (((size_t)(b * 256 + n0)) << 11);
    int arow = t & 127, ahalf = t >> 7;
    const float* asrc = Ab + (size_t)arow * 1024 + ahalf * 32;
    f32x16 acc[2][2];
    #pragma unroll
    for (int i = 0; i < 2; ++i)
        #pragma unroll
        for (int j = 0; j < 2; ++j)
            #pragma unroll
            for (int q = 0; q < 16; ++q) acc[i][j][q] = 0.f;

    float4 ar[8];
    #pragma unroll
    for (int j = 0; j < 8; ++j) ar[j] = *(const float4*)(asrc + j * 4);
    stage16(Bb, 2048, smem + 8192, wid, l);
    {
        #pragma unroll
        for (int q = 0; q < 4; ++q) {
            bf16x8 pk;
            pk[0] = (short)f2bf(ar[2*q].x);   pk[1] = (short)f2bf(ar[2*q].y);
            pk[2] = (short)f2bf(ar[2*q].z);   pk[3] = (short)f2bf(ar[2*q].w);
            pk[4] = (short)f2bf(ar[2*q+1].x); pk[5] = (short)f2bf(ar[2*q+1].y);
            pk[6] = (short)f2bf(ar[2*q+1].z); pk[7] = (short)f2bf(ar[2*q+1].w);
            int cj = ahalf * 4 + q;
            *(bf16x8*)&smem[arow * 64 + ((cj ^ (arow & 7)) << 3)] = pk;
        }
    }
    __syncthreads();
    for (int kt = 0; kt < 16; ++kt) {
        const ushort* Al = smem + (kt & 1) * 16384;
        const ushort* Bl = Al + 8192;
        ushort* nb = smem + ((kt + 1) & 1) * 16384;
        if (kt < 15) {
            #pragma unroll
            for (int j = 0; j < 8; ++j) ar[j] = *(const float4*)(asrc + (kt + 1) * 64 + j * 4);
            stage16(Bb + (kt + 1) * 128, 2048, nb + 8192, wid, l);
        }
        #pragma unroll
        for (int ks = 0; ks < 4; ++ks) {
            int kc = ks * 2 + hi;
            int mr = wr * 64 + ln, nr = wc * 64 + ln;
            bf16x8 a0 = frag(Al, mr, kc);
            bf16x8 a1 = frag(Al, mr + 32, kc);
            bf16x8 b0 = frag(Bl, nr, kc);
            bf16x8 b1 = frag(Bl, nr + 32, kc);
            acc[0][0] = __builtin_amdgcn_mfma_f32_32x32x16_bf16(a0, b0, acc[0][0], 0, 0, 0);
            acc[0][1] = __builtin_amdgcn_mfma_f32_32x32x16_bf16(a0, b1, acc[0][1], 0, 0, 0);
            acc[1][0] = __builtin_amdgcn_mfma_f32_32x32x16_bf16(a1, b0, acc[1][0], 0, 0, 0);
            acc[1][1] = __builtin_amdgcn_mfma_f32_32x32x16_bf16(a1, b1, acc[1][1], 0, 0, 0);
        }
        if (kt < 15) {
            #pragma unroll
            for (int q = 0; q < 4; ++q) {
                bf16x8 pk;
                pk[0] = (short)f2bf(ar[2*q].x);   pk[1] = (short)f2bf(ar[2*q].y);
                pk[2] = (short)f2bf(ar[2*q].z);   pk[3] = (short)f2bf(ar[2*q].w);
                pk[4] = (short)f2bf(ar[2*q+1].x); pk[5] = (short)f2bf(ar[2*q+1].y);
                pk[6] = (short)f2bf(ar[2*q+1].z); pk[7] = (short)f2bf(ar[2*q+1].w);
                int cj = ahalf * 4 + q;
                *(bf16x8*)&nb[arow * 64 + ((cj ^ (arow & 7)) << 3)] = pk;
            }
        }
        __syncthreads();
    }
    #pragma unroll
    for (int mi = 0; mi < 2; ++mi)
        #pragma unroll
        for (int ni = 0; ni < 2; ++ni) {
            int ncol = n0 + wc * 64 + ni * 32 + ln;
            #pragma unroll
            for (int r2 = 0; r2 < 4; ++r2)
                #pragma unroll
                for (int j = 0; j < 4; ++j) {
                    int mloc = wr * 64 + mi * 32 + 8 * r2 + 4 * hi + j;
                    size_t mg = (size_t)b * 1024 + m0 + mloc;
                    float v = acc[mi][ni][r2 * 4 + j] + bf2f(xt0[mg * 256 + ncol]);
                    cheb[mg * 256 + ncol] = f2bf(v);
                }
        }
}

// ---------------- K8: out[b,e,c] = relu( xg[b,c,e] + relu(cheb[b, 4e+(c>>8), c&255]) )
__global__ __launch_bounds__(256) void k_final(const ushort* __restrict__ xgb,
                                               const ushort* __restrict__ chebb,
                                               float* __restrict__ outp) {
    __shared__ ushort xl[256 * 33];
    int b = blockIdx.x >> 5;
    int et = (blockIdx.x >> 2) & 7, cb = blockIdx.x & 3;
    int e0 = et * 32, c0 = cb * 256;
    int t = threadIdx.x;
    {
        int e = t & 31, cl0 = t >> 5;
        for (int c = cl0; c < 256; c += 8)
            xl[c * 33 + e] = xgb[((size_t)b * 1024 + c0 + c) * 256 + e0 + e];
    }
    __syncthreads();
    int q4 = c0 >> 8;
    for (int el = 0; el < 32; ++el) {
        int e = e0 + el;
        float ch = bf2f(chebb[((size_t)b * 1024 + e * 4 + q4) * 256 + t]);
        float v = fmaxf(ch, 0.f);
        float xin = bf2f(xl[t * 33 + el]);
        outp[((size_t)b * 256 + e) * 1024 + c0 + t] = fmaxf(xin + v, 0.f);
    }
}

extern "C" void kernel_launch(void* const* d_in, const int* in_sizes, int n_in,
                              void* d_out, int out_size, void* d_ws, size_t ws_size,
                              hipStream_t stream) {
    const float* x     = (const float*)d_in[0];
    const float* w1    = (const float*)d_in[1];
    const float* w2    = (const float*)d_in[2];
    const float* wsi   = (const float*)d_in[3];
    const float* wqkv  = (const float*)d_in[4];
    const float* bqkv  = (const float*)d_in[5];
    const float* theta = (const float*)d_in[6];

    float* out  = (float*)d_out;
    float* badj = out + (size_t)BB * EE * CC;        // second output [32,1024,1024] fp32

    // workspace layout (bytes):
    //   xgb   bf16 [32768,256]   @ 0           (16,777,216)
    //   qk    bf16 [32768,512]   @ 16,777,216  (33,554,432)  -- cheb bf16 aliases after attn
    //   xt0   bf16 [32768,256]   @ 50,331,648  (16,777,216)
    //   xt1T  bf16 [32,256,1024] @ 67,108,864  (16,777,216)
    //   Wcat  bf16 [1024,256]    @ 83,886,080  (524,288)
    //   y0/hh/yy fp32            @ 84,410,368  (3 x 131,072)
    char* wsb = (char*)d_ws;
    ushort* xgb  = (ushort*)(wsb);
    ushort* qk   = (ushort*)(wsb + 16777216);
    ushort* cheb = (ushort*)(wsb + 16777216);
    ushort* xt0  = (ushort*)(wsb + 50331648);
    ushort* xt1T = (ushort*)(wsb + 67108864);
    ushort* Wcat = (ushort*)(wsb + 83886080);
    float* y0 = (float*)(wsb + 84410368);
    float* hh = y0 + 32768;
    float* yy = y0 + 65536;

    k_prep   <<<1024, 256, 0, stream>>>(wqkv, theta, Wcat);
    k_pool   <<<8192, 256, 0, stream>>>(x, y0);
    k_se_fc<0><<<128, 256, 0, stream>>>(y0, w1, hh);
    k_se_fc<1><<<128, 256, 0, stream>>>(hh, w2, yy);
    k_conv   <<<1024, 256, 0, stream>>>(x, wsi, yy, xgb);
    k_mm1    <<<2048, 256, 0, stream>>>(xgb, Wcat, bqkv, qk, xt0, xt1T);
    k_attn   <<<256,  256, 0, stream>>>(qk, badj);
    k_mm2    <<<512,  256, 0, stream>>>(badj, xt1T, xt0, cheb);
    k_final  <<<1024, 256, 0, stream>>>(xgb, cheb, out);
}

// Round 4
// 355.493 us; speedup vs baseline: 3.8298x; 1.0268x over previous
//
#include <hip/hip_runtime.h>

#define BB 32
#define CC 1024
#define EE 256

typedef __attribute__((ext_vector_type(8))) short bf16x8;
typedef __attribute__((ext_vector_type(16))) float f32x16;

__device__ __forceinline__ ushort f2bf(float f) {
    unsigned u = __float_as_uint(f);
    unsigned r = (u + 0x7FFFu + ((u >> 16) & 1u)) >> 16;
    return (ushort)r;
}
__device__ __forceinline__ float bf2f(ushort u) { return __uint_as_float((unsigned)u << 16); }

// stage 128 rows x 64 bf16 (128B) from global into 16KB LDS, source pre-swizzled so that
// ds_read with chunk ^= (row&7) returns linear data. LDS dest must be wave-uniform.
__device__ __forceinline__ void stage16(const char* srcBase, long stride, ushort* ldsBase,
                                        int wid, int lane) {
    #pragma unroll
    for (int i = 0; i < 4; ++i) {
        int gch = (wid * 4 + i) * 64 + lane;
        int row = gch >> 3, cj = gch & 7;
        const char* src = srcBase + (long)row * stride + ((cj ^ (row & 7)) << 4);
        __builtin_amdgcn_global_load_lds(
            (const __attribute__((address_space(1))) unsigned*)src,
            (__attribute__((address_space(3))) unsigned*)(ldsBase + (wid * 4 + i) * 512),
            16, 0, 0);
    }
}

__device__ __forceinline__ bf16x8 frag(const ushort* L, int row, int kc) {
    return *(const bf16x8*)&L[row * 64 + ((kc ^ (row & 7)) << 3)];
}

// ---------------- K1: SE adaptive-avg-pool
__global__ __launch_bounds__(256) void k_pool(const float* __restrict__ x,
                                              float* __restrict__ y0) {
    int t = threadIdx.x;
    int lane = t & 63;
    int v = blockIdx.x * 4 + (t >> 6);
    const float2* p = (const float2*)(x + (size_t)v * 128);
    float2 d = p[lane];
    float s = d.x + d.y;
    #pragma unroll
    for (int m = 1; m < 64; m <<= 1) s += __shfl_xor(s, m, 64);
    if (lane == 0) y0[v] = s * (1.0f / 128.0f);
}

// ---------------- K2/K3: SE fc layers
template <int ACT>
__global__ __launch_bounds__(256) void k_se_fc(const float* __restrict__ in,
                                               const float* __restrict__ w,
                                               float* __restrict__ outp) {
    __shared__ float yin[1024];
    int b = blockIdx.x >> 2;
    int it = blockIdx.x & 3;
    int t = threadIdx.x;
    for (int i = t; i < 1024; i += 256) yin[i] = in[b * 1024 + i];
    __syncthreads();
    int i = it * 256 + t;
    const float4* wr = (const float4*)(w + (size_t)i * 1024);
    float acc = 0.f;
    #pragma unroll 4
    for (int c4 = 0; c4 < 256; ++c4) {
        float4 wv = wr[c4];
        const float* yy = &yin[c4 * 4];
        acc += wv.x * yy[0] + wv.y * yy[1] + wv.z * yy[2] + wv.w * yy[3];
    }
    float r = (ACT == 0) ? fmaxf(acc, 0.f) : (1.f / (1.f + expf(-acc)));
    outp[b * 1024 + i] = r;
}

// ---------------- K4: fused SE-scale + 1x1 conv, bf16 output
__global__ __launch_bounds__(256) void k_conv(const float* __restrict__ x,
                                              const float* __restrict__ wsi,
                                              const float* __restrict__ y,
                                              ushort* __restrict__ xgb) {
    __shared__ __align__(16) float wsT[32 * 260];
    __shared__ __align__(16) float xl[32 * 32];
    __shared__ float sl[128];
    int b = blockIdx.x >> 5, ct = blockIdx.x & 31;
    int c0 = ct * 32;
    int t = threadIdx.x;
    if (t < 128) sl[t] = y[b * 1024 + 8 * t + (c0 >> 7)];
    int e4 = (t & 63) * 4, cq = t >> 6;
    float acc[4][8];
    #pragma unroll
    for (int i = 0; i < 4; ++i)
        #pragma unroll
        for (int j = 0; j < 8; ++j) acc[i][j] = 0.f;

    for (int lc = 0; lc < 4; ++lc) {
        __syncthreads();
        for (int idx = t; idx < 8192; idx += 256) {
            int e = idx >> 5, lp = idx & 31;
            wsT[lp * 260 + e] = wsi[e * 128 + lc * 32 + lp];
        }
        {
            int c = t & 31, l0 = t >> 5;
            for (int lp = l0; lp < 32; lp += 8)
                xl[lp * 32 + c] = x[(size_t)b * 131072 + (size_t)(lc * 32 + lp) * 1024 + c0 + c];
        }
        __syncthreads();
        for (int lp = 0; lp < 32; ++lp) {
            float s = sl[lc * 32 + lp];
            float4 wv = *(const float4*)&wsT[lp * 260 + e4];
            float4 x0 = *(const float4*)&xl[lp * 32 + cq * 8];
            float4 x1 = *(const float4*)&xl[lp * 32 + cq * 8 + 4];
            float w0 = wv.x * s, w1 = wv.y * s, w2 = wv.z * s, w3 = wv.w * s;
            float xc[8] = {x0.x, x0.y, x0.z, x0.w, x1.x, x1.y, x1.z, x1.w};
            #pragma unroll
            for (int ci = 0; ci < 8; ++ci) {
                acc[0][ci] = fmaf(w0, xc[ci], acc[0][ci]);
                acc[1][ci] = fmaf(w1, xc[ci], acc[1][ci]);
                acc[2][ci] = fmaf(w2, xc[ci], acc[2][ci]);
                acc[3][ci] = fmaf(w3, xc[ci], acc[3][ci]);
            }
        }
    }
    size_t base = (size_t)b * CC * EE;
    #pragma unroll
    for (int ci = 0; ci < 8; ++ci) {
        int c = c0 + cq * 8 + ci;
        *(ushort4*)&xgb[base + (size_t)c * EE + e4] =
            make_ushort4(f2bf(acc[0][ci]), f2bf(acc[1][ci]), f2bf(acc[2][ci]), f2bf(acc[3][ci]));
    }
}

// ---------------- K-prep: Wcat [1024][256] bf16 = [Wq; Wk; theta0^T; theta1^T]
__global__ __launch_bounds__(256) void k_prep(const float* __restrict__ W,
                                              const float* __restrict__ theta,
                                              ushort* __restrict__ Wcat) {
    int idx = blockIdx.x * 256 + threadIdx.x;
    int n = idx >> 8, k = idx & 255;
    float v;
    if (n < 512) v = W[n * 256 + k];
    else if (n < 768) v = theta[k * 256 + (n - 512)];
    else v = theta[65536 + k * 256 + (n - 768)];
    Wcat[idx] = f2bf(v);
}

// ---------------- K5: unified projection GEMM.
// out[m, n] = sum_k xg[m,k] * Wcat[n,k];  n<512 -> qk (+bias), 512..767 -> xt0, 768..1023 -> xt1T
__global__ __launch_bounds__(256) void k_mm1(const ushort* __restrict__ xgb,
                                             const ushort* __restrict__ Wcat,
                                             const float* __restrict__ bias,
                                             ushort* __restrict__ qk,
                                             ushort* __restrict__ xt0,
                                             ushort* __restrict__ xt1T) {
    __shared__ __align__(16) ushort smem[32768];   // 2 bufs x (Al 8192 + Bl 8192)
    int d = blockIdx.x;
    int xcd = d & 7, r = d >> 3;
    int mt = xcd * 32 + (r >> 3), nt = r & 7;
    int m0 = mt * 128, n0 = nt * 128;
    int t = threadIdx.x, wid = t >> 6, l = t & 63;
    int ln = l & 31, hi = l >> 5;
    int wr = wid >> 1, wc = wid & 1;
    const char* Ab = (const char*)xgb + (size_t)m0 * 512;
    const char* Bb = (const char*)Wcat + (size_t)n0 * 512;
    f32x16 acc[2][2];
    #pragma unroll
    for (int i = 0; i < 2; ++i)
        #pragma unroll
        for (int j = 0; j < 2; ++j)
            #pragma unroll
            for (int q = 0; q < 16; ++q) acc[i][j][q] = 0.f;

    stage16(Ab, 512, smem, wid, l);
    stage16(Bb, 512, smem + 8192, wid, l);
    __syncthreads();
    for (int kt = 0; kt < 4; ++kt) {
        const ushort* Al = smem + (kt & 1) * 16384;
        const ushort* Bl = Al + 8192;
        if (kt < 3) {
            ushort* nb = smem + ((kt + 1) & 1) * 16384;
            stage16(Ab + (kt + 1) * 128, 512, nb, wid, l);
            stage16(Bb + (kt + 1) * 128, 512, nb + 8192, wid, l);
        }
        #pragma unroll
        for (int ks = 0; ks < 4; ++ks) {
            int kc = ks * 2 + hi;
            int mr = wr * 64 + ln, nr = wc * 64 + ln;
            bf16x8 a0 = frag(Al, mr, kc);
            bf16x8 a1 = frag(Al, mr + 32, kc);
            bf16x8 b0 = frag(Bl, nr, kc);
            bf16x8 b1 = frag(Bl, nr + 32, kc);
            acc[0][0] = __builtin_amdgcn_mfma_f32_32x32x16_bf16(a0, b0, acc[0][0], 0, 0, 0);
            acc[0][1] = __builtin_amdgcn_mfma_f32_32x32x16_bf16(a0, b1, acc[0][1], 0, 0, 0);
            acc[1][0] = __builtin_amdgcn_mfma_f32_32x32x16_bf16(a1, b0, acc[1][0], 0, 0, 0);
            acc[1][1] = __builtin_amdgcn_mfma_f32_32x32x16_bf16(a1, b1, acc[1][1], 0, 0, 0);
        }
        __syncthreads();
    }
    if (nt < 6) {
        float bv[2] = {0.f, 0.f};
        if (nt < 4) {
            bv[0] = bias[nt * 128 + wc * 64 + ln];
            bv[1] = bias[nt * 128 + wc * 64 + 32 + ln];
        }
        #pragma unroll
        for (int mi = 0; mi < 2; ++mi)
            #pragma unroll
            for (int ni = 0; ni < 2; ++ni) {
                int ncol = wc * 64 + ni * 32 + ln;
                #pragma unroll
                for (int r2 = 0; r2 < 4; ++r2)
                    #pragma unroll
                    for (int j = 0; j < 4; ++j) {
                        int mloc = wr * 64 + mi * 32 + 8 * r2 + 4 * hi + j;
                        float v = acc[mi][ni][r2 * 4 + j] + bv[ni];
                        size_t m = (size_t)(m0 + mloc);
                        if (nt < 4) qk[m * 512 + nt * 128 + ncol] = f2bf(v);
                        else        xt0[m * 256 + (nt - 4) * 128 + ncol] = f2bf(v);
                    }
            }
    } else {
        ushort* Tl = smem;   // [128][136]
        #pragma unroll
        for (int mi = 0; mi < 2; ++mi)
            #pragma unroll
            for (int ni = 0; ni < 2; ++ni) {
                int nl = wc * 64 + ni * 32 + ln;
                #pragma unroll
                for (int r2 = 0; r2 < 4; ++r2) {
                    int mbase = wr * 64 + mi * 32 + 8 * r2 + 4 * hi;
                    ushort4 pk = make_ushort4(f2bf(acc[mi][ni][r2 * 4 + 0]),
                                              f2bf(acc[mi][ni][r2 * 4 + 1]),
                                              f2bf(acc[mi][ni][r2 * 4 + 2]),
                                              f2bf(acc[mi][ni][r2 * 4 + 3]));
                    *(ushort4*)&Tl[nl * 136 + mbase] = pk;
                }
            }
        __syncthreads();
        int n = t >> 1, mh = (t & 1) * 64;
        int bq = m0 >> 10, mib = m0 & 1023;
        ushort* dst = xt1T + (((size_t)(bq * 256 + (nt - 6) * 128 + n)) << 10) + mib + mh;
        #pragma unroll
        for (int j = 0; j < 8; ++j)
            *(uint4*)(dst + j * 8) = *(const uint4*)&Tl[n * 136 + mh + j * 8];
    }
}

// ---------------- K6a: attention partial exp-sums.
// grid 1024: qt=bid>>7, b=(bid>>2)&31, kh=bid&3. Block: 128 q-rows x 256 keys.
__global__ __launch_bounds__(256, 2) void k_attn_s(const ushort* __restrict__ qkb,
                                                   float* __restrict__ sums) {
    __shared__ __align__(16) ushort klds[2][8192];
    const float SCL2 = 0.18033688011112042f;             // log2(e)/8
    int bid = blockIdx.x;
    int qt = bid >> 7, b = (bid >> 2) & 31, kh = bid & 3;
    int t = threadIdx.x, g = t >> 6, l = t & 63;
    int col = l & 31, hi = l >> 5;
    size_t qbase = (size_t)b * 1024 * 512;
    int qrow = qt * 128 + g * 32 + col;
    int key0 = kh * 256;

    bf16x8 qa[4][4];
    #pragma unroll
    for (int h = 0; h < 4; ++h)
        #pragma unroll
        for (int kk = 0; kk < 4; ++kk)
            qa[h][kk] = *(const bf16x8*)&qkb[qbase + (size_t)qrow * 512 + h * 64 + kk * 16 + hi * 8];

    int skey = t >> 3, sd = t & 7;
    const ushort* kg = qkb + qbase + 256 + sd * 8;
    int swbase = skey * 256 + ((sd ^ (skey & 7)) << 3);

    float prsum[4][16];
    #pragma unroll
    for (int h = 0; h < 4; ++h)
        #pragma unroll
        for (int r = 0; r < 16; ++r) prsum[h][r] = 0.f;

    {
        bf16x8 st[4];
        #pragma unroll
        for (int j = 0; j < 4; ++j) st[j] = *(const bf16x8*)&kg[(size_t)(key0 + skey) * 512 + j * 64];
        #pragma unroll
        for (int j = 0; j < 4; ++j) *(bf16x8*)&klds[0][swbase + j * 64] = st[j];
    }
    __syncthreads();
    for (int kt = 0; kt < 8; ++kt) {
        bf16x8 nx[4];
        if (kt < 7) {
            #pragma unroll
            for (int j = 0; j < 4; ++j)
                nx[j] = *(const bf16x8*)&kg[(size_t)(key0 + (kt + 1) * 32 + skey) * 512 + j * 64];
        }
        const ushort* kl = &klds[kt & 1][0];
        f32x16 acc[4];
        #pragma unroll
        for (int h = 0; h < 4; ++h)
            #pragma unroll
            for (int r = 0; r < 16; ++r) acc[h][r] = 0.f;
        #pragma unroll
        for (int kk = 0; kk < 4; ++kk) {
            #pragma unroll
            for (int h = 0; h < 4; ++h) {
                bf16x8 kb = *(const bf16x8*)&kl[col * 256 + (h * 8 + ((kk * 2 + hi) ^ (col & 7))) * 8];
                acc[h] = __builtin_amdgcn_mfma_f32_32x32x16_bf16(qa[h][kk], kb, acc[h], 0, 0, 0);
            }
        }
        #pragma unroll
        for (int h = 0; h < 4; ++h)
            #pragma unroll
            for (int r = 0; r < 16; ++r)
                prsum[h][r] += exp2f(acc[h][r] * SCL2);
        if (kt < 7) {
            #pragma unroll
            for (int j = 0; j < 4; ++j) *(bf16x8*)&klds[(kt + 1) & 1][swbase + j * 64] = nx[j];
        }
        __syncthreads();
    }
    // reduce over 32 key-columns (bits 0..4 of lane), write partials
    #pragma unroll
    for (int h = 0; h < 4; ++h)
        #pragma unroll
        for (int r = 0; r < 16; ++r) {
            float s = prsum[h][r];
            s += __shfl_xor(s, 1, 64);
            s += __shfl_xor(s, 2, 64);
            s += __shfl_xor(s, 4, 64);
            s += __shfl_xor(s, 8, 64);
            s += __shfl_xor(s, 16, 64);
            prsum[h][r] = s;
        }
    if (col == 0) {
        int rowbase = qt * 128 + g * 32 + 4 * hi;
        #pragma unroll
        for (int h = 0; h < 4; ++h)
            #pragma unroll
            for (int r = 0; r < 16; ++r) {
                int row = rowbase + (r & 3) + 8 * (r >> 2);
                sums[(((size_t)b * 1024 + row) * 4 + h) * 4 + kh] = prsum[h][r];
            }
    }
}

// ---------------- K6b: attention normalize + write b_adj quarter.
__global__ __launch_bounds__(256, 2) void k_attn_w(const ushort* __restrict__ qkb,
                                                   const float* __restrict__ sums,
                                                   float* __restrict__ badj) {
    __shared__ __align__(16) ushort klds[2][8192];
    __shared__ float invL[512];
    const float SCL2 = 0.18033688011112042f;
    int bid = blockIdx.x;
    int qt = bid >> 7, b = (bid >> 2) & 31, kh = bid & 3;
    int t = threadIdx.x, g = t >> 6, l = t & 63;
    int col = l & 31, hi = l >> 5;
    size_t qbase = (size_t)b * 1024 * 512;
    int qrow = qt * 128 + g * 32 + col;
    int key0 = kh * 256;

    {
        const float4* sp = (const float4*)(sums + ((size_t)b * 1024 + qt * 128) * 16);
        #pragma unroll
        for (int i = 0; i < 2; ++i) {
            int f = t * 2 + i;
            float4 v = sp[f];
            invL[f] = 0.25f / (v.x + v.y + v.z + v.w);
        }
    }

    bf16x8 qa[4][4];
    #pragma unroll
    for (int h = 0; h < 4; ++h)
        #pragma unroll
        for (int kk = 0; kk < 4; ++kk)
            qa[h][kk] = *(const bf16x8*)&qkb[qbase + (size_t)qrow * 512 + h * 64 + kk * 16 + hi * 8];

    int skey = t >> 3, sd = t & 7;
    const ushort* kg = qkb + qbase + 256 + sd * 8;
    int swbase = skey * 256 + ((sd ^ (skey & 7)) << 3);

    {
        bf16x8 st[4];
        #pragma unroll
        for (int j = 0; j < 4; ++j) st[j] = *(const bf16x8*)&kg[(size_t)(key0 + skey) * 512 + j * 64];
        #pragma unroll
        for (int j = 0; j < 4; ++j) *(bf16x8*)&klds[0][swbase + j * 64] = st[j];
    }
    __syncthreads();

    float invr[4][16];
    #pragma unroll
    for (int h = 0; h < 4; ++h)
        #pragma unroll
        for (int r = 0; r < 16; ++r)
            invr[h][r] = invL[(g * 32 + (r & 3) + 8 * (r >> 2) + 4 * hi) * 4 + h];

    float* orow = badj + (size_t)b * 1048576 + (size_t)(qt * 128 + g * 32) * 1024;
    for (int kt = 0; kt < 8; ++kt) {
        bf16x8 nx[4];
        if (kt < 7) {
            #pragma unroll
            for (int j = 0; j < 4; ++j)
                nx[j] = *(const bf16x8*)&kg[(size_t)(key0 + (kt + 1) * 32 + skey) * 512 + j * 64];
        }
        const ushort* kl = &klds[kt & 1][0];
        f32x16 acc[4];
        #pragma unroll
        for (int h = 0; h < 4; ++h)
            #pragma unroll
            for (int r = 0; r < 16; ++r) acc[h][r] = 0.f;
        #pragma unroll
        for (int kk = 0; kk < 4; ++kk) {
            #pragma unroll
            for (int h = 0; h < 4; ++h) {
                bf16x8 kb = *(const bf16x8*)&kl[col * 256 + (h * 8 + ((kk * 2 + hi) ^ (col & 7))) * 8];
                acc[h] = __builtin_amdgcn_mfma_f32_32x32x16_bf16(qa[h][kk], kb, acc[h], 0, 0, 0);
            }
        }
        #pragma unroll
        for (int r = 0; r < 16; ++r) {
            float v = exp2f(acc[0][r] * SCL2) * invr[0][r] +
                      exp2f(acc[1][r] * SCL2) * invr[1][r] +
                      exp2f(acc[2][r] * SCL2) * invr[2][r] +
                      exp2f(acc[3][r] * SCL2) * invr[3][r];
            int row = (r & 3) + 8 * (r >> 2) + 4 * hi;
            orow[(size_t)row * 1024 + key0 + kt * 32 + col] = v;
        }
        if (kt < 7) {
            #pragma unroll
            for (int j = 0; j < 4; ++j) *(bf16x8*)&klds[(kt + 1) & 1][swbase + j * 64] = nx[j];
        }
        __syncthreads();
    }
}

// ---------------- K7: cheb = xt0 + badj @ xt1   (A: fp32 inline-converted, B: xt1T bf16)
__global__ __launch_bounds__(256) void k_mm2(const float* __restrict__ badj,
                                             const ushort* __restrict__ xt1T,
                                             const ushort* __restrict__ xt0,
                                             ushort* __restrict__ cheb) {
    __shared__ __align__(16) ushort smem[32768];
    int d = blockIdx.x;
    int xcd = d & 7, r = d >> 3;
    int lin = xcd * 64 + r;
    int b = lin >> 4, mt = (lin >> 1) & 7, nt = lin & 1;
    int m0 = mt * 128, n0 = nt * 128;
    int t = threadIdx.x, wid = t >> 6, l = t & 63;
    int ln = l & 31, hi = l >> 5;
    int wr = wid >> 1, wc = wid & 1;
    const float* Ab = badj + ((size_t)b << 20) + (size_t)m0 * 1024;
    const char* Bb = (const char*)xt1T + (((size_t)(b * 256 + n0)) << 11);
    int arow = t & 127, ahalf = t >> 7;
    const float* asrc = Ab + (size_t)arow * 1024 + ahalf * 32;
    f32x16 acc[2][2];
    #pragma unroll
    for (int i = 0; i < 2; ++i)
        #pragma unroll
        for (int j = 0; j < 2; ++j)
            #pragma unroll
            for (int q = 0; q < 16; ++q) acc[i][j][q] = 0.f;

    float4 ar[8];
    #pragma unroll
    for (int j = 0; j < 8; ++j) ar[j] = *(const float4*)(asrc + j * 4);
    stage16(Bb, 2048, smem + 8192, wid, l);
    {
        #pragma unroll
        for (int q = 0; q < 4; ++q) {
            bf16x8 pk;
            pk[0] = (short)f2bf(ar[2*q].x);   pk[1] = (short)f2bf(ar[2*q].y);
            pk[2] = (short)f2bf(ar[2*q].z);   pk[3] = (short)f2bf(ar[2*q].w);
            pk[4] = (short)f2bf(ar[2*q+1].x); pk[5] = (short)f2bf(ar[2*q+1].y);
            pk[6] = (short)f2bf(ar[2*q+1].z); pk[7] = (short)f2bf(ar[2*q+1].w);
            int cj = ahalf * 4 + q;
            *(bf16x8*)&smem[arow * 64 + ((cj ^ (arow & 7)) << 3)] = pk;
        }
    }
    __syncthreads();
    for (int kt = 0; kt < 16; ++kt) {
        const ushort* Al = smem + (kt & 1) * 16384;
        const ushort* Bl = Al + 8192;
        ushort* nb = smem + ((kt + 1) & 1) * 16384;
        if (kt < 15) {
            #pragma unroll
            for (int j = 0; j < 8; ++j) ar[j] = *(const float4*)(asrc + (kt + 1) * 64 + j * 4);
            stage16(Bb + (kt + 1) * 128, 2048, nb + 8192, wid, l);
        }
        #pragma unroll
        for (int ks = 0; ks < 4; ++ks) {
            int kc = ks * 2 + hi;
            int mr = wr * 64 + ln, nr = wc * 64 + ln;
            bf16x8 a0 = frag(Al, mr, kc);
            bf16x8 a1 = frag(Al, mr + 32, kc);
            bf16x8 b0 = frag(Bl, nr, kc);
            bf16x8 b1 = frag(Bl, nr + 32, kc);
            acc[0][0] = __builtin_amdgcn_mfma_f32_32x32x16_bf16(a0, b0, acc[0][0], 0, 0, 0);
            acc[0][1] = __builtin_amdgcn_mfma_f32_32x32x16_bf16(a0, b1, acc[0][1], 0, 0, 0);
            acc[1][0] = __builtin_amdgcn_mfma_f32_32x32x16_bf16(a1, b0, acc[1][0], 0, 0, 0);
            acc[1][1] = __builtin_amdgcn_mfma_f32_32x32x16_bf16(a1, b1, acc[1][1], 0, 0, 0);
        }
        if (kt < 15) {
            #pragma unroll
            for (int q = 0; q < 4; ++q) {
                bf16x8 pk;
                pk[0] = (short)f2bf(ar[2*q].x);   pk[1] = (short)f2bf(ar[2*q].y);
                pk[2] = (short)f2bf(ar[2*q].z);   pk[3] = (short)f2bf(ar[2*q].w);
                pk[4] = (short)f2bf(ar[2*q+1].x); pk[5] = (short)f2bf(ar[2*q+1].y);
                pk[6] = (short)f2bf(ar[2*q+1].z); pk[7] = (short)f2bf(ar[2*q+1].w);
                int cj = ahalf * 4 + q;
                *(bf16x8*)&nb[arow * 64 + ((cj ^ (arow & 7)) << 3)] = pk;
            }
        }
        __syncthreads();
    }
    #pragma unroll
    for (int mi = 0; mi < 2; ++mi)
        #pragma unroll
        for (int ni = 0; ni < 2; ++ni) {
            int ncol = n0 + wc * 64 + ni * 32 + ln;
            #pragma unroll
            for (int r2 = 0; r2 < 4; ++r2)
                #pragma unroll
                for (int j = 0; j < 4; ++j) {
                    int mloc = wr * 64 + mi * 32 + 8 * r2 + 4 * hi + j;
                    size_t mg = (size_t)b * 1024 + m0 + mloc;
                    float v = acc[mi][ni][r2 * 4 + j] + bf2f(xt0[mg * 256 + ncol]);
                    cheb[mg * 256 + ncol] = f2bf(v);
                }
        }
}

// ---------------- K8: out[b,e,c] = relu( xg[b,c,e] + relu(cheb[b, 4e+(c>>8), c&255]) )
__global__ __launch_bounds__(256) void k_final(const ushort* __restrict__ xgb,
                                               const ushort* __restrict__ chebb,
                                               float* __restrict__ outp) {
    __shared__ ushort xl[256 * 33];
    int b = blockIdx.x >> 5;
    int et = (blockIdx.x >> 2) & 7, cb = blockIdx.x & 3;
    int e0 = et * 32, c0 = cb * 256;
    int t = threadIdx.x;
    {
        int e = t & 31, cl0 = t >> 5;
        for (int c = cl0; c < 256; c += 8)
            xl[c * 33 + e] = xgb[((size_t)b * 1024 + c0 + c) * 256 + e0 + e];
    }
    __syncthreads();
    int q4 = c0 >> 8;
    for (int el = 0; el < 32; ++el) {
        int e = e0 + el;
        float ch = bf2f(chebb[((size_t)b * 1024 + e * 4 + q4) * 256 + t]);
        float v = fmaxf(ch, 0.f);
        float xin = bf2f(xl[t * 33 + el]);
        outp[((size_t)b * 256 + e) * 1024 + c0 + t] = fmaxf(xin + v, 0.f);
    }
}

extern "C" void kernel_launch(void* const* d_in, const int* in_sizes, int n_in,
                              void* d_out, int out_size, void* d_ws, size_t ws_size,
                              hipStream_t stream) {
    const float* x     = (const float*)d_in[0];
    const float* w1    = (const float*)d_in[1];
    const float* w2    = (const float*)d_in[2];
    const float* wsi   = (const float*)d_in[3];
    const float* wqkv  = (const float*)d_in[4];
    const float* bqkv  = (const float*)d_in[5];
    const float* theta = (const float*)d_in[6];

    float* out  = (float*)d_out;
    float* badj = out + (size_t)BB * EE * CC;        // second output [32,1024,1024] fp32

    // workspace layout (bytes):
    //   xgb   bf16 [32768,256]   @ 0           (16,777,216)
    //   qk    bf16 [32768,512]   @ 16,777,216  (33,554,432)  -- cheb bf16 aliases after attn
    //   xt0   bf16 [32768,256]   @ 50,331,648  (16,777,216)
    //   xt1T  bf16 [32,256,1024] @ 67,108,864  (16,777,216)
    //   Wcat  bf16 [1024,256]    @ 83,886,080  (524,288)
    //   y0/hh/yy fp32            @ 84,410,368  (3 x 131,072)
    //   sums  fp32 [32768,4,4]   @ 84,803,584  (2,097,152)
    char* wsb = (char*)d_ws;
    ushort* xgb  = (ushort*)(wsb);
    ushort* qk   = (ushort*)(wsb + 16777216);
    ushort* cheb = (ushort*)(wsb + 16777216);
    ushort* xt0  = (ushort*)(wsb + 50331648);
    ushort* xt1T = (ushort*)(wsb + 67108864);
    ushort* Wcat = (ushort*)(wsb + 83886080);
    float* y0 = (float*)(wsb + 84410368);
    float* hh = y0 + 32768;
    float* yy = y0 + 65536;
    float* sums = (float*)(wsb + 84803584);

    k_prep   <<<1024, 256, 0, stream>>>(wqkv, theta, Wcat);
    k_pool   <<<8192, 256, 0, stream>>>(x, y0);
    k_se_fc<0><<<128, 256, 0, stream>>>(y0, w1, hh);
    k_se_fc<1><<<128, 256, 0, stream>>>(hh, w2, yy);
    k_conv   <<<1024, 256, 0, stream>>>(x, wsi, yy, xgb);
    k_mm1    <<<2048, 256, 0, stream>>>(xgb, Wcat, bqkv, qk, xt0, xt1T);
    k_attn_s <<<1024, 256, 0, stream>>>(qk, sums);
    k_attn_w <<<1024, 256, 0, stream>>>(qk, sums, badj);
    k_mm2    <<<512,  256, 0, stream>>>(badj, xt1T, xt0, cheb);
    k_final  <<<1024, 256, 0, stream>>>(xgb, cheb, out);
}

// Round 5
// 325.170 us; speedup vs baseline: 4.1869x; 1.0933x over previous
//
#include <hip/hip_runtime.h>

#define BB 32
#define CC 1024
#define EE 256

typedef __attribute__((ext_vector_type(8))) short bf16x8;
typedef __attribute__((ext_vector_type(16))) float f32x16;

__device__ __forceinline__ ushort f2bf(float f) {
    unsigned u = __float_as_uint(f);
    unsigned r = (u + 0x7FFFu + ((u >> 16) & 1u)) >> 16;
    return (ushort)r;
}
__device__ __forceinline__ float bf2f(ushort u) { return __uint_as_float((unsigned)u << 16); }

// stage 128 rows x 64 bf16 (128B) from global into 16KB LDS, source pre-swizzled so that
// ds_read with chunk ^= (row&7) returns linear data. LDS dest must be wave-uniform.
__device__ __forceinline__ void stage16(const char* srcBase, long stride, ushort* ldsBase,
                                        int wid, int lane) {
    #pragma unroll
    for (int i = 0; i < 4; ++i) {
        int gch = (wid * 4 + i) * 64 + lane;
        int row = gch >> 3, cj = gch & 7;
        const char* src = srcBase + (long)row * stride + ((cj ^ (row & 7)) << 4);
        __builtin_amdgcn_global_load_lds(
            (const __attribute__((address_space(1))) unsigned*)src,
            (__attribute__((address_space(3))) unsigned*)(ldsBase + (wid * 4 + i) * 512),
            16, 0, 0);
    }
}

__device__ __forceinline__ bf16x8 frag(const ushort* L, int row, int kc) {
    return *(const bf16x8*)&L[row * 64 + ((kc ^ (row & 7)) << 3)];
}

// ---------------- K1: SE adaptive-avg-pool
__global__ __launch_bounds__(256) void k_pool(const float* __restrict__ x,
                                              float* __restrict__ y0) {
    int t = threadIdx.x;
    int lane = t & 63;
    int v = blockIdx.x * 4 + (t >> 6);
    const float2* p = (const float2*)(x + (size_t)v * 128);
    float2 d = p[lane];
    float s = d.x + d.y;
    #pragma unroll
    for (int m = 1; m < 64; m <<= 1) s += __shfl_xor(s, m, 64);
    if (lane == 0) y0[v] = s * (1.0f / 128.0f);
}

// ---------------- K2/K3: SE fc layers
template <int ACT>
__global__ __launch_bounds__(256) void k_se_fc(const float* __restrict__ in,
                                               const float* __restrict__ w,
                                               float* __restrict__ outp) {
    __shared__ float yin[1024];
    int b = blockIdx.x >> 2;
    int it = blockIdx.x & 3;
    int t = threadIdx.x;
    for (int i = t; i < 1024; i += 256) yin[i] = in[b * 1024 + i];
    __syncthreads();
    int i = it * 256 + t;
    const float4* wr = (const float4*)(w + (size_t)i * 1024);
    float acc = 0.f;
    #pragma unroll 4
    for (int c4 = 0; c4 < 256; ++c4) {
        float4 wv = wr[c4];
        const float* yy = &yin[c4 * 4];
        acc += wv.x * yy[0] + wv.y * yy[1] + wv.z * yy[2] + wv.w * yy[3];
    }
    float r = (ACT == 0) ? fmaxf(acc, 0.f) : (1.f / (1.f + expf(-acc)));
    outp[b * 1024 + i] = r;
}

// ---------------- K4: fused SE-scale + 1x1 conv, bf16 output
__global__ __launch_bounds__(256) void k_conv(const float* __restrict__ x,
                                              const float* __restrict__ wsi,
                                              const float* __restrict__ y,
                                              ushort* __restrict__ xgb) {
    __shared__ __align__(16) float wsT[32 * 260];
    __shared__ __align__(16) float xl[32 * 32];
    __shared__ float sl[128];
    int b = blockIdx.x >> 5, ct = blockIdx.x & 31;
    int c0 = ct * 32;
    int t = threadIdx.x;
    if (t < 128) sl[t] = y[b * 1024 + 8 * t + (c0 >> 7)];
    int e4 = (t & 63) * 4, cq = t >> 6;
    float acc[4][8];
    #pragma unroll
    for (int i = 0; i < 4; ++i)
        #pragma unroll
        for (int j = 0; j < 8; ++j) acc[i][j] = 0.f;

    for (int lc = 0; lc < 4; ++lc) {
        __syncthreads();
        for (int idx = t; idx < 8192; idx += 256) {
            int e = idx >> 5, lp = idx & 31;
            wsT[lp * 260 + e] = wsi[e * 128 + lc * 32 + lp];
        }
        {
            int c = t & 31, l0 = t >> 5;
            for (int lp = l0; lp < 32; lp += 8)
                xl[lp * 32 + c] = x[(size_t)b * 131072 + (size_t)(lc * 32 + lp) * 1024 + c0 + c];
        }
        __syncthreads();
        for (int lp = 0; lp < 32; ++lp) {
            float s = sl[lc * 32 + lp];
            float4 wv = *(const float4*)&wsT[lp * 260 + e4];
            float4 x0 = *(const float4*)&xl[lp * 32 + cq * 8];
            float4 x1 = *(const float4*)&xl[lp * 32 + cq * 8 + 4];
            float w0 = wv.x * s, w1 = wv.y * s, w2 = wv.z * s, w3 = wv.w * s;
            float xc[8] = {x0.x, x0.y, x0.z, x0.w, x1.x, x1.y, x1.z, x1.w};
            #pragma unroll
            for (int ci = 0; ci < 8; ++ci) {
                acc[0][ci] = fmaf(w0, xc[ci], acc[0][ci]);
                acc[1][ci] = fmaf(w1, xc[ci], acc[1][ci]);
                acc[2][ci] = fmaf(w2, xc[ci], acc[2][ci]);
                acc[3][ci] = fmaf(w3, xc[ci], acc[3][ci]);
            }
        }
    }
    size_t base = (size_t)b * CC * EE;
    #pragma unroll
    for (int ci = 0; ci < 8; ++ci) {
        int c = c0 + cq * 8 + ci;
        *(ushort4*)&xgb[base + (size_t)c * EE + e4] =
            make_ushort4(f2bf(acc[0][ci]), f2bf(acc[1][ci]), f2bf(acc[2][ci]), f2bf(acc[3][ci]));
    }
}

// ---------------- K-prep: Wcat [1024][256] bf16 = [Wq; Wk; theta0^T; theta1^T]
__global__ __launch_bounds__(256) void k_prep(const float* __restrict__ W,
                                              const float* __restrict__ theta,
                                              ushort* __restrict__ Wcat) {
    int idx = blockIdx.x * 256 + threadIdx.x;
    int n = idx >> 8, k = idx & 255;
    float v;
    if (n < 512) v = W[n * 256 + k];
    else if (n < 768) v = theta[k * 256 + (n - 512)];
    else v = theta[65536 + k * 256 + (n - 768)];
    Wcat[idx] = f2bf(v);
}

// ---------------- K5: unified projection GEMM.
// out[m, n] = sum_k xg[m,k] * Wcat[n,k];  n<512 -> qk (+bias), 512..767 -> xt0, 768..1023 -> xt1T
__global__ __launch_bounds__(256) void k_mm1(const ushort* __restrict__ xgb,
                                             const ushort* __restrict__ Wcat,
                                             const float* __restrict__ bias,
                                             ushort* __restrict__ qk,
                                             ushort* __restrict__ xt0,
                                             ushort* __restrict__ xt1T) {
    __shared__ __align__(16) ushort smem[32768];   // 2 bufs x (Al 8192 + Bl 8192)
    int d = blockIdx.x;
    int xcd = d & 7, r = d >> 3;
    int mt = xcd * 32 + (r >> 3), nt = r & 7;
    int m0 = mt * 128, n0 = nt * 128;
    int t = threadIdx.x, wid = t >> 6, l = t & 63;
    int ln = l & 31, hi = l >> 5;
    int wr = wid >> 1, wc = wid & 1;
    const char* Ab = (const char*)xgb + (size_t)m0 * 512;
    const char* Bb = (const char*)Wcat + (size_t)n0 * 512;
    f32x16 acc[2][2];
    #pragma unroll
    for (int i = 0; i < 2; ++i)
        #pragma unroll
        for (int j = 0; j < 2; ++j)
            #pragma unroll
            for (int q = 0; q < 16; ++q) acc[i][j][q] = 0.f;

    stage16(Ab, 512, smem, wid, l);
    stage16(Bb, 512, smem + 8192, wid, l);
    __syncthreads();
    for (int kt = 0; kt < 4; ++kt) {
        const ushort* Al = smem + (kt & 1) * 16384;
        const ushort* Bl = Al + 8192;
        if (kt < 3) {
            ushort* nb = smem + ((kt + 1) & 1) * 16384;
            stage16(Ab + (kt + 1) * 128, 512, nb, wid, l);
            stage16(Bb + (kt + 1) * 128, 512, nb + 8192, wid, l);
        }
        __builtin_amdgcn_s_setprio(1);
        #pragma unroll
        for (int ks = 0; ks < 4; ++ks) {
            int kc = ks * 2 + hi;
            int mr = wr * 64 + ln, nr = wc * 64 + ln;
            bf16x8 a0 = frag(Al, mr, kc);
            bf16x8 a1 = frag(Al, mr + 32, kc);
            bf16x8 b0 = frag(Bl, nr, kc);
            bf16x8 b1 = frag(Bl, nr + 32, kc);
            acc[0][0] = __builtin_amdgcn_mfma_f32_32x32x16_bf16(a0, b0, acc[0][0], 0, 0, 0);
            acc[0][1] = __builtin_amdgcn_mfma_f32_32x32x16_bf16(a0, b1, acc[0][1], 0, 0, 0);
            acc[1][0] = __builtin_amdgcn_mfma_f32_32x32x16_bf16(a1, b0, acc[1][0], 0, 0, 0);
            acc[1][1] = __builtin_amdgcn_mfma_f32_32x32x16_bf16(a1, b1, acc[1][1], 0, 0, 0);
        }
        __builtin_amdgcn_s_setprio(0);
        __syncthreads();
    }
    if (nt < 6) {
        float bv[2] = {0.f, 0.f};
        if (nt < 4) {
            bv[0] = bias[nt * 128 + wc * 64 + ln];
            bv[1] = bias[nt * 128 + wc * 64 + 32 + ln];
        }
        #pragma unroll
        for (int mi = 0; mi < 2; ++mi)
            #pragma unroll
            for (int ni = 0; ni < 2; ++ni) {
                int ncol = wc * 64 + ni * 32 + ln;
                #pragma unroll
                for (int r2 = 0; r2 < 4; ++r2)
                    #pragma unroll
                    for (int j = 0; j < 4; ++j) {
                        int mloc = wr * 64 + mi * 32 + 8 * r2 + 4 * hi + j;
                        float v = acc[mi][ni][r2 * 4 + j] + bv[ni];
                        size_t m = (size_t)(m0 + mloc);
                        if (nt < 4) qk[m * 512 + nt * 128 + ncol] = f2bf(v);
                        else        xt0[m * 256 + (nt - 4) * 128 + ncol] = f2bf(v);
                    }
            }
    } else {
        ushort* Tl = smem;   // [128][136]
        #pragma unroll
        for (int mi = 0; mi < 2; ++mi)
            #pragma unroll
            for (int ni = 0; ni < 2; ++ni) {
                int nl = wc * 64 + ni * 32 + ln;
                #pragma unroll
                for (int r2 = 0; r2 < 4; ++r2) {
                    int mbase = wr * 64 + mi * 32 + 8 * r2 + 4 * hi;
                    ushort4 pk = make_ushort4(f2bf(acc[mi][ni][r2 * 4 + 0]),
                                              f2bf(acc[mi][ni][r2 * 4 + 1]),
                                              f2bf(acc[mi][ni][r2 * 4 + 2]),
                                              f2bf(acc[mi][ni][r2 * 4 + 3]));
                    *(ushort4*)&Tl[nl * 136 + mbase] = pk;
                }
            }
        __syncthreads();
        int n = t >> 1, mh = (t & 1) * 64;
        int bq = m0 >> 10, mib = m0 & 1023;
        ushort* dst = xt1T + (((size_t)(bq * 256 + (nt - 6) * 128 + n)) << 10) + mib + mh;
        #pragma unroll
        for (int j = 0; j < 8; ++j)
            *(uint4*)(dst + j * 8) = *(const uint4*)&Tl[n * 136 + mh + j * 8];
    }
}

// ---------------- K6a: attention partial exp-sums (head-pair split).
// grid 2048: qt=bid>>8, b=(bid>>3)&31, kh=(bid>>1)&3, hp=bid&1.
// Block: 128 q-rows x 256 keys x 2 heads.
__global__ __launch_bounds__(256, 3) void k_attn_s(const ushort* __restrict__ qkb,
                                                   float* __restrict__ sums) {
    __shared__ __align__(16) ushort klds[2][4096];       // [buf][32 keys][128 d swz]
    const float SCL2 = 0.18033688011112042f;             // log2(e)/8
    int bid = blockIdx.x;
    int qt = bid >> 8, b = (bid >> 3) & 31, kh = (bid >> 1) & 3, hp = bid & 1;
    int t = threadIdx.x, g = t >> 6, l = t & 63;
    int wid = g;
    int col = l & 31, hi = l >> 5;
    size_t qbase = (size_t)b * 1024 * 512;
    int qrow = qt * 128 + g * 32 + col;
    int key0 = kh * 256;

    bf16x8 qa[2][4];
    #pragma unroll
    for (int hh = 0; hh < 2; ++hh)
        #pragma unroll
        for (int kk = 0; kk < 4; ++kk)
            qa[hh][kk] = *(const bf16x8*)&qkb[qbase + (size_t)qrow * 512 +
                                             (hp * 2 + hh) * 64 + kk * 16 + hi * 8];

    // stage: 32 keys x 128 d (head-pair slice) = 8KB, 512 x 16B chunks, 2/thread
    const char* kgb = (const char*)(qkb + qbase + 256 + hp * 128);
    auto stage_k = [&](int kt, ushort* dst) {
        #pragma unroll
        for (int i = 0; i < 2; ++i) {
            int gidx = i * 256 + wid * 64 + l;
            int row = gidx >> 4, c = gidx & 15;
            const char* src = kgb + (size_t)(key0 + kt * 32 + row) * 1024 +
                              (((c >> 3) << 7) + (((c & 7) ^ (row & 7)) << 4));
            __builtin_amdgcn_global_load_lds(
                (const __attribute__((address_space(1))) unsigned*)src,
                (__attribute__((address_space(3))) unsigned*)(dst + (i * 256 + wid * 64) * 8),
                16, 0, 0);
        }
    };

    float prsum[2][16];
    #pragma unroll
    for (int hh = 0; hh < 2; ++hh)
        #pragma unroll
        for (int r = 0; r < 16; ++r) prsum[hh][r] = 0.f;

    stage_k(0, klds[0]);
    __syncthreads();
    for (int kt = 0; kt < 8; ++kt) {
        if (kt < 7) stage_k(kt + 1, klds[(kt + 1) & 1]);
        const ushort* kl = &klds[kt & 1][0];
        f32x16 acc[2];
        #pragma unroll
        for (int hh = 0; hh < 2; ++hh)
            #pragma unroll
            for (int r = 0; r < 16; ++r) acc[hh][r] = 0.f;
        __builtin_amdgcn_s_setprio(1);
        #pragma unroll
        for (int kk = 0; kk < 4; ++kk) {
            #pragma unroll
            for (int hh = 0; hh < 2; ++hh) {
                bf16x8 kb = *(const bf16x8*)&kl[col * 128 +
                                               (hh * 8 + ((kk * 2 + hi) ^ (col & 7))) * 8];
                acc[hh] = __builtin_amdgcn_mfma_f32_32x32x16_bf16(qa[hh][kk], kb, acc[hh], 0, 0, 0);
            }
        }
        __builtin_amdgcn_s_setprio(0);
        #pragma unroll
        for (int hh = 0; hh < 2; ++hh)
            #pragma unroll
            for (int r = 0; r < 16; ++r)
                prsum[hh][r] += exp2f(acc[hh][r] * SCL2);
        __syncthreads();
    }
    #pragma unroll
    for (int hh = 0; hh < 2; ++hh)
        #pragma unroll
        for (int r = 0; r < 16; ++r) {
            float s = prsum[hh][r];
            s += __shfl_xor(s, 1, 64);
            s += __shfl_xor(s, 2, 64);
            s += __shfl_xor(s, 4, 64);
            s += __shfl_xor(s, 8, 64);
            s += __shfl_xor(s, 16, 64);
            prsum[hh][r] = s;
        }
    if (col == 0) {
        int rowbase = qt * 128 + g * 32 + 4 * hi;
        #pragma unroll
        for (int hh = 0; hh < 2; ++hh)
            #pragma unroll
            for (int r = 0; r < 16; ++r) {
                int row = rowbase + (r & 3) + 8 * (r >> 2);
                sums[(((size_t)b * 1024 + row) * 4 + hp * 2 + hh) * 4 + kh] = prsum[hh][r];
            }
    }
}

// ---------------- K6b: attention normalize + write b_adj (fp32) and pb (bf16).
// grid 1024: qt=bid>>7, b=(bid>>2)&31, kh=bid&3.
__global__ __launch_bounds__(256, 2) void k_attn_w(const ushort* __restrict__ qkb,
                                                   const float* __restrict__ sums,
                                                   float* __restrict__ badj,
                                                   ushort* __restrict__ pb) {
    __shared__ __align__(16) ushort klds[2][8192];
    __shared__ float invL[512];
    const float SCL2 = 0.18033688011112042f;
    int bid = blockIdx.x;
    int qt = bid >> 7, b = (bid >> 2) & 31, kh = bid & 3;
    int t = threadIdx.x, g = t >> 6, l = t & 63;
    int wid = g;
    int col = l & 31, hi = l >> 5;
    size_t qbase = (size_t)b * 1024 * 512;
    int qrow = qt * 128 + g * 32 + col;
    int key0 = kh * 256;

    {
        const float4* sp = (const float4*)(sums + ((size_t)b * 1024 + qt * 128) * 16);
        #pragma unroll
        for (int i = 0; i < 2; ++i) {
            int f = t * 2 + i;
            float4 v = sp[f];
            invL[f] = 0.25f / (v.x + v.y + v.z + v.w);
        }
    }

    bf16x8 qa[4][4];
    #pragma unroll
    for (int h = 0; h < 4; ++h)
        #pragma unroll
        for (int kk = 0; kk < 4; ++kk)
            qa[h][kk] = *(const bf16x8*)&qkb[qbase + (size_t)qrow * 512 + h * 64 + kk * 16 + hi * 8];

    // stage: 32 keys x 256 d = 16KB, 1024 x 16B chunks, 4/thread
    const char* kgb = (const char*)(qkb + qbase + 256);
    auto stage_k = [&](int kt, ushort* dst) {
        #pragma unroll
        for (int i = 0; i < 4; ++i) {
            int gidx = i * 256 + wid * 64 + l;
            int row = gidx >> 5, c = gidx & 31;
            const char* src = kgb + (size_t)(key0 + kt * 32 + row) * 1024 +
                              (((c >> 3) << 7) + (((c & 7) ^ (row & 7)) << 4));
            __builtin_amdgcn_global_load_lds(
                (const __attribute__((address_space(1))) unsigned*)src,
                (__attribute__((address_space(3))) unsigned*)(dst + (i * 256 + wid * 64) * 8),
                16, 0, 0);
        }
    };

    stage_k(0, klds[0]);
    __syncthreads();

    float invr[4][16];
    #pragma unroll
    for (int h = 0; h < 4; ++h)
        #pragma unroll
        for (int r = 0; r < 16; ++r)
            invr[h][r] = invL[(g * 32 + (r & 3) + 8 * (r >> 2) + 4 * hi) * 4 + h];

    float* orow = badj + ((size_t)b << 20) + (size_t)(qt * 128 + g * 32) * 1024;
    ushort* prow = pb + ((size_t)b << 20) + (size_t)(qt * 128 + g * 32) * 1024;
    for (int kt = 0; kt < 8; ++kt) {
        if (kt < 7) stage_k(kt + 1, klds[(kt + 1) & 1]);
        const ushort* kl = &klds[kt & 1][0];
        f32x16 acc[4];
        #pragma unroll
        for (int h = 0; h < 4; ++h)
            #pragma unroll
            for (int r = 0; r < 16; ++r) acc[h][r] = 0.f;
        __builtin_amdgcn_s_setprio(1);
        #pragma unroll
        for (int kk = 0; kk < 4; ++kk) {
            #pragma unroll
            for (int h = 0; h < 4; ++h) {
                bf16x8 kb = *(const bf16x8*)&kl[col * 256 + (h * 8 + ((kk * 2 + hi) ^ (col & 7))) * 8];
                acc[h] = __builtin_amdgcn_mfma_f32_32x32x16_bf16(qa[h][kk], kb, acc[h], 0, 0, 0);
            }
        }
        __builtin_amdgcn_s_setprio(0);
        #pragma unroll
        for (int r = 0; r < 16; ++r) {
            float v = exp2f(acc[0][r] * SCL2) * invr[0][r] +
                      exp2f(acc[1][r] * SCL2) * invr[1][r] +
                      exp2f(acc[2][r] * SCL2) * invr[2][r] +
                      exp2f(acc[3][r] * SCL2) * invr[3][r];
            int row = (r & 3) + 8 * (r >> 2) + 4 * hi;
            size_t idx = (size_t)row * 1024 + key0 + kt * 32 + col;
            orow[idx] = v;
            prow[idx] = f2bf(v);
        }
        __syncthreads();
    }
}

// ---------------- K7: cheb = xt0 + pb @ xt1   (A: pb bf16 via stage16, B: xt1T bf16)
__global__ __launch_bounds__(256) void k_mm2(const ushort* __restrict__ pb,
                                             const ushort* __restrict__ xt1T,
                                             const ushort* __restrict__ xt0,
                                             ushort* __restrict__ cheb) {
    __shared__ __align__(16) ushort smem[32768];
    int d = blockIdx.x;
    int xcd = d & 7, r = d >> 3;
    int lin = xcd * 64 + r;
    int b = lin >> 4, mt = (lin >> 1) & 7, nt = lin & 1;
    int m0 = mt * 128, n0 = nt * 128;
    int t = threadIdx.x, wid = t >> 6, l = t & 63;
    int ln = l & 31, hi = l >> 5;
    int wr = wid >> 1, wc = wid & 1;
    const char* Ab = (const char*)pb + ((size_t)b << 21) + (size_t)m0 * 2048;
    const char* Bb = (const char*)xt1T + (((size_t)(b * 256 + n0)) << 11);
    f32x16 acc[2][2];
    #pragma unroll
    for (int i = 0; i < 2; ++i)
        #pragma unroll
        for (int j = 0; j < 2; ++j)
            #pragma unroll
            for (int q = 0; q < 16; ++q) acc[i][j][q] = 0.f;

    stage16(Ab, 2048, smem, wid, l);
    stage16(Bb, 2048, smem + 8192, wid, l);
    __syncthreads();
    for (int kt = 0; kt < 16; ++kt) {
        const ushort* Al = smem + (kt & 1) * 16384;
        const ushort* Bl = Al + 8192;
        if (kt < 15) {
            ushort* nb = smem + ((kt + 1) & 1) * 16384;
            stage16(Ab + (kt + 1) * 128, 2048, nb, wid, l);
            stage16(Bb + (kt + 1) * 128, 2048, nb + 8192, wid, l);
        }
        __builtin_amdgcn_s_setprio(1);
        #pragma unroll
        for (int ks = 0; ks < 4; ++ks) {
            int kc = ks * 2 + hi;
            int mr = wr * 64 + ln, nr = wc * 64 + ln;
            bf16x8 a0 = frag(Al, mr, kc);
            bf16x8 a1 = frag(Al, mr + 32, kc);
            bf16x8 b0 = frag(Bl, nr, kc);
            bf16x8 b1 = frag(Bl, nr + 32, kc);
            acc[0][0] = __builtin_amdgcn_mfma_f32_32x32x16_bf16(a0, b0, acc[0][0], 0, 0, 0);
            acc[0][1] = __builtin_amdgcn_mfma_f32_32x32x16_bf16(a0, b1, acc[0][1], 0, 0, 0);
            acc[1][0] = __builtin_amdgcn_mfma_f32_32x32x16_bf16(a1, b0, acc[1][0], 0, 0, 0);
            acc[1][1] = __builtin_amdgcn_mfma_f32_32x32x16_bf16(a1, b1, acc[1][1], 0, 0, 0);
        }
        __builtin_amdgcn_s_setprio(0);
        __syncthreads();
    }
    #pragma unroll
    for (int mi = 0; mi < 2; ++mi)
        #pragma unroll
        for (int ni = 0; ni < 2; ++ni) {
            int ncol = n0 + wc * 64 + ni * 32 + ln;
            #pragma unroll
            for (int r2 = 0; r2 < 4; ++r2)
                #pragma unroll
                for (int j = 0; j < 4; ++j) {
                    int mloc = wr * 64 + mi * 32 + 8 * r2 + 4 * hi + j;
                    size_t mg = (size_t)b * 1024 + m0 + mloc;
                    float v = acc[mi][ni][r2 * 4 + j] + bf2f(xt0[mg * 256 + ncol]);
                    cheb[mg * 256 + ncol] = f2bf(v);
                }
        }
}

// ---------------- K8: out[b,e,c] = relu( xg[b,c,e] + relu(cheb[b, 4e+(c>>8), c&255]) )
__global__ __launch_bounds__(256) void k_final(const ushort* __restrict__ xgb,
                                               const ushort* __restrict__ chebb,
                                               float* __restrict__ outp) {
    __shared__ ushort xl[256 * 33];
    int b = blockIdx.x >> 5;
    int et = (blockIdx.x >> 2) & 7, cb = blockIdx.x & 3;
    int e0 = et * 32, c0 = cb * 256;
    int t = threadIdx.x;
    {
        int e = t & 31, cl0 = t >> 5;
        for (int c = cl0; c < 256; c += 8)
            xl[c * 33 + e] = xgb[((size_t)b * 1024 + c0 + c) * 256 + e0 + e];
    }
    __syncthreads();
    int q4 = c0 >> 8;
    for (int el = 0; el < 32; ++el) {
        int e = e0 + el;
        float ch = bf2f(chebb[((size_t)b * 1024 + e * 4 + q4) * 256 + t]);
        float v = fmaxf(ch, 0.f);
        float xin = bf2f(xl[t * 33 + el]);
        outp[((size_t)b * 256 + e) * 1024 + c0 + t] = fmaxf(xin + v, 0.f);
    }
}

extern "C" void kernel_launch(void* const* d_in, const int* in_sizes, int n_in,
                              void* d_out, int out_size, void* d_ws, size_t ws_size,
                              hipStream_t stream) {
    const float* x     = (const float*)d_in[0];
    const float* w1    = (const float*)d_in[1];
    const float* w2    = (const float*)d_in[2];
    const float* wsi   = (const float*)d_in[3];
    const float* wqkv  = (const float*)d_in[4];
    const float* bqkv  = (const float*)d_in[5];
    const float* theta = (const float*)d_in[6];

    float* out  = (float*)d_out;
    float* badj = out + (size_t)BB * EE * CC;        // second output [32,1024,1024] fp32

    // workspace (128 MiB exactly):
    //   xgb  bf16 [32768,256]   @ 0           (16,777,216)
    //   qk   bf16 [32768,512]   @ 16,777,216  (33,554,432)  -- cheb bf16 aliases after attn_w
    //   xt0  bf16 [32768,256]   @ 50,331,648  (16,777,216)
    //   pb   bf16 [32,1024,1024]@ 67,108,864  (67,108,864)
    // out1-region of d_out (33.5 MB, dead until k_final) holds the small scratch:
    //   xt1T bf16 [32,256,1024] @ out+0          (16,777,216)
    //   sums fp32 [32768,4,4]   @ out+16,777,216 (2,097,152)
    //   Wcat bf16 [1024,256]    @ out+18,874,368 (524,288)
    //   y0/hh/yy fp32           @ out+19,398,656 (3 x 131,072)
    char* wsb = (char*)d_ws;
    ushort* xgb  = (ushort*)(wsb);
    ushort* qk   = (ushort*)(wsb + 16777216);
    ushort* cheb = (ushort*)(wsb + 16777216);
    ushort* xt0  = (ushort*)(wsb + 50331648);
    ushort* pb   = (ushort*)(wsb + 67108864);

    char* osc = (char*)d_out;
    ushort* xt1T = (ushort*)(osc);
    float*  sums = (float*)(osc + 16777216);
    ushort* Wcat = (ushort*)(osc + 18874368);
    float* y0 = (float*)(osc + 19398656);
    float* hh = y0 + 32768;
    float* yy = y0 + 65536;

    k_prep   <<<1024, 256, 0, stream>>>(wqkv, theta, Wcat);
    k_pool   <<<8192, 256, 0, stream>>>(x, y0);
    k_se_fc<0><<<128, 256, 0, stream>>>(y0, w1, hh);
    k_se_fc<1><<<128, 256, 0, stream>>>(hh, w2, yy);
    k_conv   <<<1024, 256, 0, stream>>>(x, wsi, yy, xgb);
    k_mm1    <<<2048, 256, 0, stream>>>(xgb, Wcat, bqkv, qk, xt0, xt1T);
    k_attn_s <<<2048, 256, 0, stream>>>(qk, sums);
    k_attn_w <<<1024, 256, 0, stream>>>(qk, sums, badj, pb);
    k_mm2    <<<512,  256, 0, stream>>>(pb, xt1T, xt0, cheb);
    k_final  <<<1024, 256, 0, stream>>>(xgb, cheb, out);
}